// Round 1
// baseline (252.544 us; speedup 1.0000x reference)
//
#include <hip/hip_runtime.h>

#define NPOLY 256
#define VPP   64
#define LCH   32
#define NV    (1 + NPOLY * VPP)
#define LN_EPS 1e-5f

typedef __bf16 bf16x8 __attribute__((ext_vector_type(8)));
typedef float  f32x4  __attribute__((ext_vector_type(4)));

union U4B8 { uint4 u; bf16x8 v; };

// hardware RNE pack: lo=bf16(a), hi=bf16(b)  (same rounding as manual f2bf_u)
__device__ __forceinline__ unsigned packbf(float a, float b) {
    unsigned r;
    asm("v_cvt_pk_bf16_f32 %0, %1, %2" : "=v"(r) : "v"(a), "v"(b));
    return r;
}

// ---------------------------------------------------------------------------
// prep1: (a) fold Wq/Wk/Wv over the duplicated 128-channel halves of P,
//        (b) pack W0 / W1-top / W2-top into bf16 B-fragment order:
//        frag f, lane L: 8 bf16 = W[k0 + j][ct*16 + (L&15)], k0 = (L>>4)*8 (+ks*32)
//        stored as 64 x uint4 per fragment (1 KB) -> one coalesced b128/lane.
// ---------------------------------------------------------------------------
__global__ void vn_prep1(const float* __restrict__ W0, const float* __restrict__ W1,
                         const float* __restrict__ W2,
                         const float* __restrict__ Wq, const float* __restrict__ Wk,
                         const float* __restrict__ Wv,
                         float* __restrict__ Wqf, float* __restrict__ Wkf,
                         float* __restrict__ Wvf, uint4* __restrict__ wpack)
{
    int t = blockIdx.x * 256 + threadIdx.x;
    if (t < 3 * 32768) {
        int which = t >> 15, r = t & 32767;    // r = i*256+c, i<128
        const float* src = which == 0 ? Wq : which == 1 ? Wk : Wv;
        float*       dst = which == 0 ? Wqf : which == 1 ? Wkf : Wvf;
        dst[r] = src[r] + src[r + 128 * 256];
        return;
    }
    t -= 3 * 32768;
    if (t >= 22 * 64) return;
    int f = t >> 6, L = t & 63, q = L >> 4, m = L & 15;
    const float* src; int N, k0, col;
    if (f < 2)      { src = W0; N = 32;  k0 = q * 8;                 col = f * 16 + m; }
    else if (f < 6) { src = W1; N = 64;  k0 = q * 8;                 col = (f - 2) * 16 + m; }
    else { int g = f - 6; src = W2; N = 128; k0 = (g >> 3) * 32 + q * 8; col = (g & 7) * 16 + m; }
    float e[8];
    #pragma unroll
    for (int j = 0; j < 8; j++) e[j] = src[(k0 + j) * N + col];
    uint4 o;
    o.x = packbf(e[0], e[1]); o.y = packbf(e[2], e[3]);
    o.z = packbf(e[4], e[5]); o.w = packbf(e[6], e[7]);
    wpack[f * 64 + L] = o;
}

// ---------------------------------------------------------------------------
// prep2: Mff[i][j] = sum_c Wqf[i][c] * Wkf[j][c]   (128x128, K=256)
//        u0f[j]    = sum_c bq[c]    * Wkf[j][c]
// float4 loads + 4 independent FMA chains (was one 256-deep chain).
// ---------------------------------------------------------------------------
__global__ void vn_prep2(const float* __restrict__ Wqf, const float* __restrict__ Wkf,
                         const float* __restrict__ bq,
                         float* __restrict__ Mff, float* __restrict__ u0f)
{
    int t = blockIdx.x * 256 + threadIdx.x;
    if (t < 16384) {
        int i = t >> 7, j = t & 127;
        const float4* a = (const float4*)(Wqf + i * 256);
        const float4* b = (const float4*)(Wkf + j * 256);
        float s0 = 0.f, s1 = 0.f, s2 = 0.f, s3 = 0.f;
        #pragma unroll 4
        for (int c = 0; c < 64; c++) {
            float4 A = a[c], B = b[c];
            s0 = fmaf(A.x, B.x, s0); s1 = fmaf(A.y, B.y, s1);
            s2 = fmaf(A.z, B.z, s2); s3 = fmaf(A.w, B.w, s3);
        }
        Mff[i * 128 + j] = (s0 + s1) + (s2 + s3);
    } else if (t < 16512) {
        int j = t - 16384;
        const float4* a = (const float4*)bq;
        const float4* b = (const float4*)(Wkf + j * 256);
        float s0 = 0.f, s1 = 0.f, s2 = 0.f, s3 = 0.f;
        #pragma unroll 4
        for (int c = 0; c < 64; c++) {
            float4 A = a[c], B = b[c];
            s0 = fmaf(A.x, B.x, s0); s1 = fmaf(A.y, B.y, s1);
            s2 = fmaf(A.z, B.z, s2); s3 = fmaf(A.w, B.w, s3);
        }
        u0f[j] = (s0 + s1) + (s2 + s3);
    }
}

// ---------------------------------------------------------------------------
// vn_mlp: 4 waves per block, one poly per wave, private LDS slice per wave.
// No __syncthreads: all producer/consumer LDS traffic is intra-wave
// (DS ops are in-order per wave; wave_barrier pins the scheduler).
// MFMA 16x16x32 bf16; C/D layout col=lane&15,row=(lane>>4)*4+reg (m89);
// A layout A[m=lane&15][k=(lane>>4)*8+j] (m120).
// ---------------------------------------------------------------------------
__global__ __launch_bounds__(256, 4) void vn_mlp(
    const float* __restrict__ data, const uint4* __restrict__ wpack,
    const float* __restrict__ b0, const float* __restrict__ g0, const float* __restrict__ be0,
    const float* __restrict__ W1, const float* __restrict__ b1,
    const float* __restrict__ g1, const float* __restrict__ be1,
    const float* __restrict__ W2, const float* __restrict__ b2,
    const float* __restrict__ g2, const float* __restrict__ be2,
    float* __restrict__ Ph)
{
    __shared__ __align__(16) unsigned short hbuf[4][64 * 72];  // 9216 B / wave
    __shared__ float fbuf[4][192];   // [0,64): agg bcast, [64,192): au bcast

    const int w = threadIdx.x >> 6;
    const int L = threadIdx.x & 63, q = L >> 4, m = L & 15;
    const int blk = blockIdx.x * 4 + w;           // poly index (b*256+p)
    const int bb = blk >> 8, pp = blk & 255;
    unsigned short* hb = hbuf[w];
    float* fb = fbuf[w];

    // ---------------- layer 0 : 32 -> 32 ----------------
    const float* rowbase = data + ((size_t)bb * NV + 1 + (size_t)pp * VPP) * LCH;
    bf16x8 A0[4];
    #pragma unroll
    for (int rt = 0; rt < 4; rt++) {
        const float* rp = rowbase + (size_t)(rt * 16 + m) * LCH + q * 8;
        float4 u = *(const float4*)rp;
        float4 v = *(const float4*)(rp + 4);
        if (q == 3) v.w = 0.f;                 // vecs[:, :, -1] = 0
        U4B8 c;
        c.u.x = packbf(u.x, u.y); c.u.y = packbf(u.z, u.w);
        c.u.z = packbf(v.x, v.y); c.u.w = packbf(v.z, v.w);
        A0[rt] = c.v;
    }
    U4B8 t0, t1; t0.u = wpack[0 * 64 + L]; t1.u = wpack[1 * 64 + L];
    float bc0[2] = { b0[m], b0[16 + m] };
    f32x4 acc0[4][2];
    #pragma unroll
    for (int rt = 0; rt < 4; rt++) {
        {
            f32x4 a = { bc0[0], bc0[0], bc0[0], bc0[0] };
            acc0[rt][0] = __builtin_amdgcn_mfma_f32_16x16x32_bf16(A0[rt], t0.v, a, 0, 0, 0);
        }
        {
            f32x4 a = { bc0[1], bc0[1], bc0[1], bc0[1] };
            acc0[rt][1] = __builtin_amdgcn_mfma_f32_16x16x32_bf16(A0[rt], t1.v, a, 0, 0, 0);
        }
    }
    // LN (per row, N=32) + relu + col-max
    float g0c[2]  = { g0[m],  g0[16 + m]  };
    float be0c[2] = { be0[m], be0[16 + m] };
    float a0mx[2] = { 0.f, 0.f };
    #pragma unroll
    for (int rt = 0; rt < 4; rt++) {
        #pragma unroll
        for (int reg = 0; reg < 4; reg++) {
            float x0 = acc0[rt][0][reg], x1 = acc0[rt][1][reg];
            float rs = x0 + x1, rq = x0 * x0 + x1 * x1;
            #pragma unroll
            for (int s = 1; s < 16; s <<= 1) { rs += __shfl_xor(rs, s, 64); rq += __shfl_xor(rq, s, 64); }
            float mu = rs * (1.f / 32.f);
            float var = rq * (1.f / 32.f) - mu * mu;
            float ri = rsqrtf(var + LN_EPS);
            #pragma unroll
            for (int ct = 0; ct < 2; ct++) {
                float v = fmaxf(fmaf(g0c[ct] * ri, acc0[rt][ct][reg] - mu, be0c[ct]), 0.f);
                acc0[rt][ct][reg] = v;
                a0mx[ct] = fmaxf(a0mx[ct], v);
            }
        }
    }
    #pragma unroll
    for (int ct = 0; ct < 2; ct++) {
        float v = a0mx[ct];
        v = fmaxf(v, __shfl_xor(v, 16, 64));
        v = fmaxf(v, __shfl_xor(v, 32, 64));
        a0mx[ct] = v;
    }
    if (q == 0) { fb[m] = a0mx[0]; fb[16 + m] = a0mx[1]; }
    __builtin_amdgcn_wave_barrier();
    // uniform part: au1[n=L] = b1[L] + sum_j agg0[j] * W1[32+j][L]  (2 chains)
    float au1a = b1[L], au1b = 0.f;
    for (int j = 0; j < 32; j += 2) {
        au1a = fmaf(fb[j],     W1[(32 + j) * 64 + L],     au1a);
        au1b = fmaf(fb[j + 1], W1[(32 + j + 1) * 64 + L], au1b);
    }
    float au1 = au1a + au1b;
    // stage h0 (bf16) for next layer's A-fragments
    #pragma unroll
    for (int rt = 0; rt < 4; rt++)
        #pragma unroll
        for (int reg = 0; reg < 4; reg++) {
            int row = rt * 16 + q * 4 + reg;
            unsigned u = packbf(acc0[rt][0][reg], acc0[rt][1][reg]);
            hb[row * 72 + m]      = (unsigned short)u;
            hb[row * 72 + 16 + m] = (unsigned short)(u >> 16);
        }
    __builtin_amdgcn_wave_barrier();
    fb[64 + L] = au1;
    __builtin_amdgcn_wave_barrier();

    // ---------------- layer 1 : 64(per-row 32) -> 64 ----------------
    bf16x8 A1[4];
    #pragma unroll
    for (int rt = 0; rt < 4; rt++) {
        U4B8 c; c.u = *(const uint4*)(hb + (rt * 16 + m) * 72 + q * 8);
        A1[rt] = c.v;
    }
    f32x4 acc1[4][4];
    #pragma unroll
    for (int ct = 0; ct < 4; ct++) {
        U4B8 wv; wv.u = wpack[(2 + ct) * 64 + L];
        float au = fb[64 + ct * 16 + m];
        #pragma unroll
        for (int rt = 0; rt < 4; rt++) {
            f32x4 a = { au, au, au, au };
            acc1[rt][ct] = __builtin_amdgcn_mfma_f32_16x16x32_bf16(A1[rt], wv.v, a, 0, 0, 0);
        }
    }
    float g1c[4], be1c[4];
    #pragma unroll
    for (int ct = 0; ct < 4; ct++) { g1c[ct] = g1[ct * 16 + m]; be1c[ct] = be1[ct * 16 + m]; }
    float a1mx[4] = { 0.f, 0.f, 0.f, 0.f };
    #pragma unroll
    for (int rt = 0; rt < 4; rt++) {
        #pragma unroll
        for (int reg = 0; reg < 4; reg++) {
            float rs = 0.f, rq = 0.f;
            #pragma unroll
            for (int ct = 0; ct < 4; ct++) { float x = acc1[rt][ct][reg]; rs += x; rq += x * x; }
            #pragma unroll
            for (int s = 1; s < 16; s <<= 1) { rs += __shfl_xor(rs, s, 64); rq += __shfl_xor(rq, s, 64); }
            float mu = rs * (1.f / 64.f);
            float var = rq * (1.f / 64.f) - mu * mu;
            float ri = rsqrtf(var + LN_EPS);
            #pragma unroll
            for (int ct = 0; ct < 4; ct++) {
                float v = fmaxf(fmaf(g1c[ct] * ri, acc1[rt][ct][reg] - mu, be1c[ct]), 0.f);
                acc1[rt][ct][reg] = v;
                a1mx[ct] = fmaxf(a1mx[ct], v);
            }
        }
    }
    #pragma unroll
    for (int ct = 0; ct < 4; ct++) {
        float v = a1mx[ct];
        v = fmaxf(v, __shfl_xor(v, 16, 64));
        v = fmaxf(v, __shfl_xor(v, 32, 64));
        a1mx[ct] = v;
    }
    __builtin_amdgcn_wave_barrier();
    if (q == 0) {
        #pragma unroll
        for (int ct = 0; ct < 4; ct++) fb[ct * 16 + m] = a1mx[ct];
    }
    __builtin_amdgcn_wave_barrier();
    // au2: 4 independent chains
    float au2a = b2[L], au2b = b2[64 + L], au2c = 0.f, au2d = 0.f;
    for (int j = 0; j < 64; j += 2) {
        float av0 = fb[j], av1 = fb[j + 1];
        au2a = fmaf(av0, W2[(64 + j) * 128 + L],          au2a);
        au2b = fmaf(av0, W2[(64 + j) * 128 + 64 + L],     au2b);
        au2c = fmaf(av1, W2[(64 + j + 1) * 128 + L],      au2c);
        au2d = fmaf(av1, W2[(64 + j + 1) * 128 + 64 + L], au2d);
    }
    au2a += au2c; au2b += au2d;
    #pragma unroll
    for (int rt = 0; rt < 4; rt++)
        #pragma unroll
        for (int reg = 0; reg < 4; reg++) {
            int row = rt * 16 + q * 4 + reg;
            unsigned ua = packbf(acc1[rt][0][reg], acc1[rt][1][reg]);
            unsigned ub = packbf(acc1[rt][2][reg], acc1[rt][3][reg]);
            hb[row * 72 + m]      = (unsigned short)ua;
            hb[row * 72 + 16 + m] = (unsigned short)(ua >> 16);
            hb[row * 72 + 32 + m] = (unsigned short)ub;
            hb[row * 72 + 48 + m] = (unsigned short)(ub >> 16);
        }
    __builtin_amdgcn_wave_barrier();
    fb[64 + L] = au2a; fb[128 + L] = au2b;
    __builtin_amdgcn_wave_barrier();

    // ---------------- layer 2 : 128(per-row 64) -> 128 ----------------
    bf16x8 A2[4][2];
    #pragma unroll
    for (int rt = 0; rt < 4; rt++)
        #pragma unroll
        for (int ks = 0; ks < 2; ks++) {
            U4B8 c; c.u = *(const uint4*)(hb + (rt * 16 + m) * 72 + ks * 32 + q * 8);
            A2[rt][ks] = c.v;
        }
    f32x4 acc2[8][4];
    #pragma unroll
    for (int ct = 0; ct < 8; ct++) {
        U4B8 wa, wb;
        wa.u = wpack[(6 + ct) * 64 + L];
        wb.u = wpack[(14 + ct) * 64 + L];
        float au = fb[64 + ct * 16 + m];
        #pragma unroll
        for (int rt = 0; rt < 4; rt++) {
            f32x4 a = { au, au, au, au };
            a = __builtin_amdgcn_mfma_f32_16x16x32_bf16(A2[rt][0], wa.v, a, 0, 0, 0);
            a = __builtin_amdgcn_mfma_f32_16x16x32_bf16(A2[rt][1], wb.v, a, 0, 0, 0);
            acc2[ct][rt] = a;
        }
    }
    float g2c[8], be2c[8];
    #pragma unroll
    for (int ct = 0; ct < 8; ct++) { g2c[ct] = g2[ct * 16 + m]; be2c[ct] = be2[ct * 16 + m]; }
    float m2[8] = { 0.f, 0.f, 0.f, 0.f, 0.f, 0.f, 0.f, 0.f };
    #pragma unroll
    for (int rt = 0; rt < 4; rt++) {
        #pragma unroll
        for (int reg = 0; reg < 4; reg++) {
            float rs = 0.f, rq = 0.f;
            #pragma unroll
            for (int ct = 0; ct < 8; ct++) { float x = acc2[ct][rt][reg]; rs += x; rq += x * x; }
            #pragma unroll
            for (int s = 1; s < 16; s <<= 1) { rs += __shfl_xor(rs, s, 64); rq += __shfl_xor(rq, s, 64); }
            float mu = rs * (1.f / 128.f);
            float var = rq * (1.f / 128.f) - mu * mu;
            float ri = rsqrtf(var + LN_EPS);
            #pragma unroll
            for (int ct = 0; ct < 8; ct++) {
                float v = fmaxf(fmaf(g2c[ct] * ri, acc2[ct][rt][reg] - mu, be2c[ct]), 0.f);
                m2[ct] = fmaxf(m2[ct], v);
            }
        }
    }
    #pragma unroll
    for (int ct = 0; ct < 8; ct++) {
        float v = m2[ct];
        v = fmaxf(v, __shfl_xor(v, 16, 64));
        v = fmaxf(v, __shfl_xor(v, 32, 64));
        m2[ct] = v;
    }
    // lane L stores cols L and 64+L:  col = (q or 4+q)*16 + m
    float v1 = q == 0 ? m2[0] : q == 1 ? m2[1] : q == 2 ? m2[2] : m2[3];
    float v2 = q == 0 ? m2[4] : q == 1 ? m2[5] : q == 2 ? m2[6] : m2[7];
    float* op = Ph + (size_t)blk * 128;
    op[L] = v1; op[64 + L] = v2;
}

// ---------------------------------------------------------------------------
// vn_attn: per-batch tail on folded matrices.
// All serial inner products restructured to 4 independent FMA chains;
// scores: one poly per thread (no per-p cross-lane reductions).
// ---------------------------------------------------------------------------
__global__ __launch_bounds__(256) void vn_attn(
    const float* __restrict__ data, const float* __restrict__ Ph,
    const float* __restrict__ Mff, const float* __restrict__ u0f,
    const float* __restrict__ Wvf, const float* __restrict__ bv,
    float* __restrict__ out)
{
    __shared__ __align__(16) float pah[128], tts[128], att[256], pb[128];
    __shared__ __align__(16) float part[256];
    __shared__ float red[8];
    const int b = blockIdx.x, tid = threadIdx.x, lane = tid & 63, wave = tid >> 6;
    const float* PhB = Ph + (size_t)b * NPOLY * 128;
    const int agent = (int)data[(size_t)b * NV * LCH];

    if (tid < 128) pah[tid] = PhB[(size_t)agent * 128 + tid];
    __syncthreads();

    // tts[j] = u0f[j] + sum_i pah[i]*Mff[i][j]; i-range split over 2 halves
    {
        const int j = tid & 127, h = tid >> 7;
        const float* mc = Mff + (size_t)(h * 64) * 128 + j;
        const float* pv = pah + h * 64;
        float s0 = 0.f, s1 = 0.f, s2 = 0.f, s3 = 0.f;
        for (int i = 0; i < 64; i += 4) {
            s0 = fmaf(pv[i],     mc[(i)     * 128], s0);
            s1 = fmaf(pv[i + 1], mc[(i + 1) * 128], s1);
            s2 = fmaf(pv[i + 2], mc[(i + 2) * 128], s2);
            s3 = fmaf(pv[i + 3], mc[(i + 3) * 128], s3);
        }
        part[tid] = (s0 + s1) + (s2 + s3);
    }
    __syncthreads();
    if (tid < 128) tts[tid] = part[tid] + part[128 + tid] + u0f[tid];
    __syncthreads();

    // scores: thread tid handles poly p = tid
    float sv;
    {
        const float* pr = PhB + (size_t)tid * 128;
        float s0 = 0.f, s1 = 0.f, s2 = 0.f, s3 = 0.f;
        for (int j = 0; j < 128; j += 16) {
            float4 x0 = *(const float4*)(pr + j);
            float4 x1 = *(const float4*)(pr + j + 4);
            float4 x2 = *(const float4*)(pr + j + 8);
            float4 x3 = *(const float4*)(pr + j + 12);
            float4 t0 = *(const float4*)(tts + j);
            float4 t1 = *(const float4*)(tts + j + 4);
            float4 t2 = *(const float4*)(tts + j + 8);
            float4 t3 = *(const float4*)(tts + j + 12);
            s0 = fmaf(x0.w, t0.w, fmaf(x0.z, t0.z, fmaf(x0.y, t0.y, fmaf(x0.x, t0.x, s0))));
            s1 = fmaf(x1.w, t1.w, fmaf(x1.z, t1.z, fmaf(x1.y, t1.y, fmaf(x1.x, t1.x, s1))));
            s2 = fmaf(x2.w, t2.w, fmaf(x2.z, t2.z, fmaf(x2.y, t2.y, fmaf(x2.x, t2.x, s2))));
            s3 = fmaf(x3.w, t3.w, fmaf(x3.z, t3.z, fmaf(x3.y, t3.y, fmaf(x3.x, t3.x, s3))));
        }
        sv = ((s0 + s1) + (s2 + s3)) * 0.0625f;
    }
    // softmax over 256 scores
    float mx = sv;
    #pragma unroll
    for (int s = 1; s < 64; s <<= 1) mx = fmaxf(mx, __shfl_xor(mx, s, 64));
    if (lane == 0) red[wave] = mx;
    __syncthreads();
    mx = fmaxf(fmaxf(red[0], red[1]), fmaxf(red[2], red[3]));
    float e = expf(sv - mx);
    float sm = e;
    #pragma unroll
    for (int s = 1; s < 64; s <<= 1) sm += __shfl_xor(sm, s, 64);
    if (lane == 0) red[4 + wave] = sm;
    __syncthreads();
    const float tot = red[4] + red[5] + red[6] + red[7];
    att[tid] = e / tot;
    __syncthreads();

    // pb[c] = sum_p att[p]*PhB[p][c]; p-range split over 2 halves
    {
        const int c = tid & 127, h = tid >> 7;
        const float* pp = PhB + (size_t)(h * 128) * 128 + c;
        const float* ap = att + h * 128;
        float s0 = 0.f, s1 = 0.f, s2 = 0.f, s3 = 0.f;
        for (int p = 0; p < 128; p += 4) {
            s0 = fmaf(ap[p],     pp[(p)     * 128], s0);
            s1 = fmaf(ap[p + 1], pp[(p + 1) * 128], s1);
            s2 = fmaf(ap[p + 2], pp[(p + 2) * 128], s2);
            s3 = fmaf(ap[p + 3], pp[(p + 3) * 128], s3);
        }
        part[tid] = (s0 + s1) + (s2 + s3);
    }
    __syncthreads();
    if (tid < 128) pb[tid] = part[tid] + part[128 + tid];
    __syncthreads();

    // out[c] = bv[c] + sum_j pb[j]*Wvf[j][c]
    {
        const float* wv = Wvf + tid;
        float s0 = 0.f, s1 = 0.f, s2 = 0.f, s3 = 0.f;
        for (int j = 0; j < 128; j += 4) {
            s0 = fmaf(pb[j],     wv[(j)     * 256], s0);
            s1 = fmaf(pb[j + 1], wv[(j + 1) * 256], s1);
            s2 = fmaf(pb[j + 2], wv[(j + 2) * 256], s2);
            s3 = fmaf(pb[j + 3], wv[(j + 3) * 256], s3);
        }
        out[(size_t)b * 256 + tid] = bv[tid] + ((s0 + s1) + (s2 + s3));
    }
}

extern "C" void kernel_launch(void* const* d_in, const int* in_sizes, int n_in,
                              void* d_out, int out_size, void* d_ws, size_t ws_size,
                              hipStream_t stream)
{
    const float* data = (const float*)d_in[0];
    const float* W0 = (const float*)d_in[1];
    const float* b0 = (const float*)d_in[2];
    const float* g0 = (const float*)d_in[3];
    const float* be0= (const float*)d_in[4];
    const float* W1 = (const float*)d_in[5];
    const float* b1 = (const float*)d_in[6];
    const float* g1 = (const float*)d_in[7];
    const float* be1= (const float*)d_in[8];
    const float* W2 = (const float*)d_in[9];
    const float* b2 = (const float*)d_in[10];
    const float* g2 = (const float*)d_in[11];
    const float* be2= (const float*)d_in[12];
    const float* Wq = (const float*)d_in[13];
    const float* bq = (const float*)d_in[14];
    const float* Wk = (const float*)d_in[15];
    const float* bk = (const float*)d_in[16];
    const float* Wv = (const float*)d_in[17];
    const float* bv = (const float*)d_in[18];
    (void)bk;

    char* wsb = (char*)d_ws;
    float* Ph    = (float*)(wsb);                  // 4 MB
    float* Wqf   = (float*)(wsb + 4194304);        // 128 KB
    float* Wkf   = (float*)(wsb + 4325376);        // 128 KB
    float* Wvf   = (float*)(wsb + 4456448);        // 128 KB
    float* Mff   = (float*)(wsb + 4587520);        // 64 KB
    float* u0f   = (float*)(wsb + 4653056);        // 512 B
    uint4* wpack = (uint4*)(wsb + 4653568);        // 22 KB

    vn_prep1<<<390, 256, 0, stream>>>(W0, W1, W2, Wq, Wk, Wv, Wqf, Wkf, Wvf, wpack);
    vn_prep2<<<65, 256, 0, stream>>>(Wqf, Wkf, bq, Mff, u0f);
    vn_mlp<<<32 * NPOLY / 4, 256, 0, stream>>>(data, wpack,
                                               b0, g0, be0,
                                               W1, b1, g1, be1,
                                               W2, b2, g2, be2, Ph);
    vn_attn<<<32, 256, 0, stream>>>(data, Ph, Mff, u0f, Wvf, bv, (float*)d_out);
}

// Round 2
// 234.121 us; speedup vs baseline: 1.0787x; 1.0787x over previous
//
#include <hip/hip_runtime.h>

#define NPOLY 256
#define VPP   64
#define LCH   32
#define NV    (1 + NPOLY * VPP)
#define LN_EPS 1e-5f

typedef __bf16 bf16x8 __attribute__((ext_vector_type(8)));
typedef float  f32x4  __attribute__((ext_vector_type(4)));

union U4B8 { uint4 u; bf16x8 v; };

// hardware RNE pack: lo=bf16(a), hi=bf16(b)  (same rounding as manual round-nearest-even)
__device__ __forceinline__ unsigned packbf(float a, float b) {
    unsigned r;
    asm("v_cvt_pk_bf16_f32 %0, %1, %2" : "=v"(r) : "v"(a), "v"(b));
    return r;
}

// ---------------------------------------------------------------------------
// prep1: (a) fold Wq/Wk/Wv over the duplicated 128-channel halves of P,
//        (b) pack W0 / W1-top / W2-top into bf16 B-fragment order:
//        frag f, lane L: 8 bf16 = W[k0 + j][ct*16 + (L&15)], k0 = (L>>4)*8 (+ks*32)
//        stored as 64 x uint4 per fragment (1 KB) -> one coalesced b128/lane.
// ---------------------------------------------------------------------------
__global__ void vn_prep1(const float* __restrict__ W0, const float* __restrict__ W1,
                         const float* __restrict__ W2,
                         const float* __restrict__ Wq, const float* __restrict__ Wk,
                         const float* __restrict__ Wv,
                         float* __restrict__ Wqf, float* __restrict__ Wkf,
                         float* __restrict__ Wvf, uint4* __restrict__ wpack)
{
    int t = blockIdx.x * 256 + threadIdx.x;
    if (t < 3 * 32768) {
        int which = t >> 15, r = t & 32767;    // r = i*256+c, i<128
        const float* src = which == 0 ? Wq : which == 1 ? Wk : Wv;
        float*       dst = which == 0 ? Wqf : which == 1 ? Wkf : Wvf;
        dst[r] = src[r] + src[r + 128 * 256];
        return;
    }
    t -= 3 * 32768;
    if (t >= 22 * 64) return;
    int f = t >> 6, L = t & 63, q = L >> 4, m = L & 15;
    const float* src; int N, k0, col;
    if (f < 2)      { src = W0; N = 32;  k0 = q * 8;                 col = f * 16 + m; }
    else if (f < 6) { src = W1; N = 64;  k0 = q * 8;                 col = (f - 2) * 16 + m; }
    else { int g = f - 6; src = W2; N = 128; k0 = (g >> 3) * 32 + q * 8; col = (g & 7) * 16 + m; }
    float e[8];
    #pragma unroll
    for (int j = 0; j < 8; j++) e[j] = src[(k0 + j) * N + col];
    uint4 o;
    o.x = packbf(e[0], e[1]); o.y = packbf(e[2], e[3]);
    o.z = packbf(e[4], e[5]); o.w = packbf(e[6], e[7]);
    wpack[f * 64 + L] = o;
}

// ---------------------------------------------------------------------------
// prep2: Mff[i][j] = sum_c Wqf[i][c] * Wkf[j][c]   (128x128, K=256)
//        u0f[j]    = sum_c bq[c]    * Wkf[j][c]
// float4 loads + 4 independent FMA chains.
// ---------------------------------------------------------------------------
__global__ void vn_prep2(const float* __restrict__ Wqf, const float* __restrict__ Wkf,
                         const float* __restrict__ bq,
                         float* __restrict__ Mff, float* __restrict__ u0f)
{
    int t = blockIdx.x * 256 + threadIdx.x;
    if (t < 16384) {
        int i = t >> 7, j = t & 127;
        const float4* a = (const float4*)(Wqf + i * 256);
        const float4* b = (const float4*)(Wkf + j * 256);
        float s0 = 0.f, s1 = 0.f, s2 = 0.f, s3 = 0.f;
        #pragma unroll 4
        for (int c = 0; c < 64; c++) {
            float4 A = a[c], B = b[c];
            s0 = fmaf(A.x, B.x, s0); s1 = fmaf(A.y, B.y, s1);
            s2 = fmaf(A.z, B.z, s2); s3 = fmaf(A.w, B.w, s3);
        }
        Mff[i * 128 + j] = (s0 + s1) + (s2 + s3);
    } else if (t < 16512) {
        int j = t - 16384;
        const float4* a = (const float4*)bq;
        const float4* b = (const float4*)(Wkf + j * 256);
        float s0 = 0.f, s1 = 0.f, s2 = 0.f, s3 = 0.f;
        #pragma unroll 4
        for (int c = 0; c < 64; c++) {
            float4 A = a[c], B = b[c];
            s0 = fmaf(A.x, B.x, s0); s1 = fmaf(A.y, B.y, s1);
            s2 = fmaf(A.z, B.z, s2); s3 = fmaf(A.w, B.w, s3);
        }
        u0f[j] = (s0 + s1) + (s2 + s3);
    }
}

// ---------------------------------------------------------------------------
// vn_mlp: one wave per poly, MFMA 16x16x32 bf16.
// C/D layout (m89): col = lane&15, row = (lane>>4)*4 + reg.
// A layout (m120): A[m = lane&15][k = (lane>>4)*8 + j].
// Layer 2 is TWO-PASS to cut peak live registers (~230 -> ~130):
//   pass A: accumulate row sum / sumsq with one ct-tile accumulator live;
//   pass B: recompute the MFMAs (matrix pipe is ~5% busy, recompute free)
//           and apply LN + column-max with mu/ri live.
// launch_bounds(64,3): 12 waves/CU, zero spill at ~168-reg cap.
// ---------------------------------------------------------------------------
__global__ __launch_bounds__(64, 3) void vn_mlp(
    const float* __restrict__ data, const uint4* __restrict__ wpack,
    const float* __restrict__ b0, const float* __restrict__ g0, const float* __restrict__ be0,
    const float* __restrict__ W1, const float* __restrict__ b1,
    const float* __restrict__ g1, const float* __restrict__ be1,
    const float* __restrict__ W2, const float* __restrict__ b2,
    const float* __restrict__ g2, const float* __restrict__ be2,
    float* __restrict__ Ph)
{
    __shared__ __align__(16) unsigned short hbuf[64 * 72];  // 9216 B
    __shared__ float fbuf[192];   // [0,64): agg bcast, [64,192): au bcast

    const int blk = blockIdx.x;
    const int L = threadIdx.x, q = L >> 4, m = L & 15;
    const int bb = blk >> 8, pp = blk & 255;

    // ---------------- layer 0 : 32 -> 32 ----------------
    const float* rowbase = data + ((size_t)bb * NV + 1 + (size_t)pp * VPP) * LCH;
    bf16x8 A0[4];
    #pragma unroll
    for (int rt = 0; rt < 4; rt++) {
        const float* rp = rowbase + (size_t)(rt * 16 + m) * LCH + q * 8;
        float4 u = *(const float4*)rp;
        float4 v = *(const float4*)(rp + 4);
        if (q == 3) v.w = 0.f;                 // vecs[:, :, -1] = 0
        U4B8 c;
        c.u.x = packbf(u.x, u.y); c.u.y = packbf(u.z, u.w);
        c.u.z = packbf(v.x, v.y); c.u.w = packbf(v.z, v.w);
        A0[rt] = c.v;
    }
    U4B8 t0, t1; t0.u = wpack[0 * 64 + L]; t1.u = wpack[1 * 64 + L];
    float bc0[2] = { b0[m], b0[16 + m] };
    f32x4 acc0[4][2];
    #pragma unroll
    for (int rt = 0; rt < 4; rt++) {
        {
            f32x4 a = { bc0[0], bc0[0], bc0[0], bc0[0] };
            acc0[rt][0] = __builtin_amdgcn_mfma_f32_16x16x32_bf16(A0[rt], t0.v, a, 0, 0, 0);
        }
        {
            f32x4 a = { bc0[1], bc0[1], bc0[1], bc0[1] };
            acc0[rt][1] = __builtin_amdgcn_mfma_f32_16x16x32_bf16(A0[rt], t1.v, a, 0, 0, 0);
        }
    }
    // LN (per row, N=32) + relu + col-max
    float g0c[2]  = { g0[m],  g0[16 + m]  };
    float be0c[2] = { be0[m], be0[16 + m] };
    float a0mx[2] = { 0.f, 0.f };
    #pragma unroll
    for (int rt = 0; rt < 4; rt++) {
        #pragma unroll
        for (int reg = 0; reg < 4; reg++) {
            float x0 = acc0[rt][0][reg], x1 = acc0[rt][1][reg];
            float rs = x0 + x1, rq = x0 * x0 + x1 * x1;
            #pragma unroll
            for (int s = 1; s < 16; s <<= 1) { rs += __shfl_xor(rs, s, 64); rq += __shfl_xor(rq, s, 64); }
            float mu = rs * (1.f / 32.f);
            float var = rq * (1.f / 32.f) - mu * mu;
            float ri = rsqrtf(var + LN_EPS);
            #pragma unroll
            for (int ct = 0; ct < 2; ct++) {
                float v = fmaxf(fmaf(g0c[ct] * ri, acc0[rt][ct][reg] - mu, be0c[ct]), 0.f);
                acc0[rt][ct][reg] = v;
                a0mx[ct] = fmaxf(a0mx[ct], v);
            }
        }
    }
    #pragma unroll
    for (int ct = 0; ct < 2; ct++) {
        float v = a0mx[ct];
        v = fmaxf(v, __shfl_xor(v, 16, 64));
        v = fmaxf(v, __shfl_xor(v, 32, 64));
        a0mx[ct] = v;
    }
    if (q == 0) { fbuf[m] = a0mx[0]; fbuf[16 + m] = a0mx[1]; }
    __builtin_amdgcn_wave_barrier();
    // uniform part: au1[n=L] = b1[L] + sum_j agg0[j] * W1[32+j][L]  (2 chains)
    float au1a = b1[L], au1b = 0.f;
    for (int j = 0; j < 32; j += 2) {
        au1a = fmaf(fbuf[j],     W1[(32 + j) * 64 + L],     au1a);
        au1b = fmaf(fbuf[j + 1], W1[(32 + j + 1) * 64 + L], au1b);
    }
    float au1 = au1a + au1b;
    // stage h0 (bf16) for next layer's A-fragments
    #pragma unroll
    for (int rt = 0; rt < 4; rt++)
        #pragma unroll
        for (int reg = 0; reg < 4; reg++) {
            int row = rt * 16 + q * 4 + reg;
            unsigned u = packbf(acc0[rt][0][reg], acc0[rt][1][reg]);
            hbuf[row * 72 + m]      = (unsigned short)u;
            hbuf[row * 72 + 16 + m] = (unsigned short)(u >> 16);
        }
    __builtin_amdgcn_wave_barrier();
    fbuf[64 + L] = au1;
    __builtin_amdgcn_wave_barrier();

    // ---------------- layer 1 : 64(per-row 32) -> 64 ----------------
    bf16x8 A1[4];
    #pragma unroll
    for (int rt = 0; rt < 4; rt++) {
        U4B8 c; c.u = *(const uint4*)(hbuf + (rt * 16 + m) * 72 + q * 8);
        A1[rt] = c.v;
    }
    f32x4 acc1[4][4];
    #pragma unroll
    for (int ct = 0; ct < 4; ct++) {
        U4B8 wv; wv.u = wpack[(2 + ct) * 64 + L];
        float au = fbuf[64 + ct * 16 + m];
        #pragma unroll
        for (int rt = 0; rt < 4; rt++) {
            f32x4 a = { au, au, au, au };
            acc1[rt][ct] = __builtin_amdgcn_mfma_f32_16x16x32_bf16(A1[rt], wv.v, a, 0, 0, 0);
        }
    }
    float g1c[4], be1c[4];
    #pragma unroll
    for (int ct = 0; ct < 4; ct++) { g1c[ct] = g1[ct * 16 + m]; be1c[ct] = be1[ct * 16 + m]; }
    float a1mx[4] = { 0.f, 0.f, 0.f, 0.f };
    #pragma unroll
    for (int rt = 0; rt < 4; rt++) {
        #pragma unroll
        for (int reg = 0; reg < 4; reg++) {
            float rs = 0.f, rq = 0.f;
            #pragma unroll
            for (int ct = 0; ct < 4; ct++) { float x = acc1[rt][ct][reg]; rs += x; rq += x * x; }
            #pragma unroll
            for (int s = 1; s < 16; s <<= 1) { rs += __shfl_xor(rs, s, 64); rq += __shfl_xor(rq, s, 64); }
            float mu = rs * (1.f / 64.f);
            float var = rq * (1.f / 64.f) - mu * mu;
            float ri = rsqrtf(var + LN_EPS);
            #pragma unroll
            for (int ct = 0; ct < 4; ct++) {
                float v = fmaxf(fmaf(g1c[ct] * ri, acc1[rt][ct][reg] - mu, be1c[ct]), 0.f);
                acc1[rt][ct][reg] = v;
                a1mx[ct] = fmaxf(a1mx[ct], v);
            }
        }
    }
    #pragma unroll
    for (int ct = 0; ct < 4; ct++) {
        float v = a1mx[ct];
        v = fmaxf(v, __shfl_xor(v, 16, 64));
        v = fmaxf(v, __shfl_xor(v, 32, 64));
        a1mx[ct] = v;
    }
    __builtin_amdgcn_wave_barrier();
    if (q == 0) {
        #pragma unroll
        for (int ct = 0; ct < 4; ct++) fbuf[ct * 16 + m] = a1mx[ct];
    }
    __builtin_amdgcn_wave_barrier();
    // au2: 4 independent chains
    float au2a = b2[L], au2b = b2[64 + L], au2c = 0.f, au2d = 0.f;
    for (int j = 0; j < 64; j += 2) {
        float av0 = fbuf[j], av1 = fbuf[j + 1];
        au2a = fmaf(av0, W2[(64 + j) * 128 + L],          au2a);
        au2b = fmaf(av0, W2[(64 + j) * 128 + 64 + L],     au2b);
        au2c = fmaf(av1, W2[(64 + j + 1) * 128 + L],      au2c);
        au2d = fmaf(av1, W2[(64 + j + 1) * 128 + 64 + L], au2d);
    }
    au2a += au2c; au2b += au2d;
    #pragma unroll
    for (int rt = 0; rt < 4; rt++)
        #pragma unroll
        for (int reg = 0; reg < 4; reg++) {
            int row = rt * 16 + q * 4 + reg;
            unsigned ua = packbf(acc1[rt][0][reg], acc1[rt][1][reg]);
            unsigned ub = packbf(acc1[rt][2][reg], acc1[rt][3][reg]);
            hbuf[row * 72 + m]      = (unsigned short)ua;
            hbuf[row * 72 + 16 + m] = (unsigned short)(ua >> 16);
            hbuf[row * 72 + 32 + m] = (unsigned short)ub;
            hbuf[row * 72 + 48 + m] = (unsigned short)(ub >> 16);
        }
    __builtin_amdgcn_wave_barrier();
    fbuf[64 + L] = au2a; fbuf[128 + L] = au2b;
    __builtin_amdgcn_wave_barrier();

    // ---------------- layer 2 : 128(per-row 64) -> 128, TWO-PASS ----------------
    bf16x8 A2[4][2];
    #pragma unroll
    for (int rt = 0; rt < 4; rt++)
        #pragma unroll
        for (int ks = 0; ks < 2; ks++) {
            U4B8 c; c.u = *(const uint4*)(hbuf + (rt * 16 + m) * 72 + ks * 32 + q * 8);
            A2[rt][ks] = c.v;
        }
    // pass A: row sum / sumsq, one ct-tile accumulator live at a time
    f32x4 rsum[4] = {}, rqsum[4] = {};
    #pragma unroll
    for (int ct = 0; ct < 8; ct++) {
        U4B8 wa, wb;
        wa.u = wpack[(6 + ct) * 64 + L];
        wb.u = wpack[(14 + ct) * 64 + L];
        float au = fbuf[64 + ct * 16 + m];
        #pragma unroll
        for (int rt = 0; rt < 4; rt++) {
            f32x4 a = { au, au, au, au };
            a = __builtin_amdgcn_mfma_f32_16x16x32_bf16(A2[rt][0], wa.v, a, 0, 0, 0);
            a = __builtin_amdgcn_mfma_f32_16x16x32_bf16(A2[rt][1], wb.v, a, 0, 0, 0);
            rsum[rt] += a;
            rqsum[rt] += a * a;
        }
    }
    f32x4 muv[4], riv[4];
    #pragma unroll
    for (int rt = 0; rt < 4; rt++) {
        #pragma unroll
        for (int reg = 0; reg < 4; reg++) {
            float rs = rsum[rt][reg], rq = rqsum[rt][reg];
            #pragma unroll
            for (int s = 1; s < 16; s <<= 1) { rs += __shfl_xor(rs, s, 64); rq += __shfl_xor(rq, s, 64); }
            float mu = rs * (1.f / 128.f);
            float var = rq * (1.f / 128.f) - mu * mu;
            muv[rt][reg] = mu;
            riv[rt][reg] = rsqrtf(var + LN_EPS);
        }
    }
    // pass B: recompute MFMAs (bit-identical), apply LN + column max
    float g2c[8], be2c[8];
    #pragma unroll
    for (int ct = 0; ct < 8; ct++) { g2c[ct] = g2[ct * 16 + m]; be2c[ct] = be2[ct * 16 + m]; }
    float m2[8] = { 0.f, 0.f, 0.f, 0.f, 0.f, 0.f, 0.f, 0.f };
    #pragma unroll
    for (int ct = 0; ct < 8; ct++) {
        U4B8 wa, wb;
        wa.u = wpack[(6 + ct) * 64 + L];
        wb.u = wpack[(14 + ct) * 64 + L];
        float au = fbuf[64 + ct * 16 + m];
        #pragma unroll
        for (int rt = 0; rt < 4; rt++) {
            f32x4 a = { au, au, au, au };
            a = __builtin_amdgcn_mfma_f32_16x16x32_bf16(A2[rt][0], wa.v, a, 0, 0, 0);
            a = __builtin_amdgcn_mfma_f32_16x16x32_bf16(A2[rt][1], wb.v, a, 0, 0, 0);
            #pragma unroll
            for (int reg = 0; reg < 4; reg++) {
                float v = fmaxf(fmaf(g2c[ct] * riv[rt][reg], a[reg] - muv[rt][reg], be2c[ct]), 0.f);
                m2[ct] = fmaxf(m2[ct], v);
            }
        }
    }
    #pragma unroll
    for (int ct = 0; ct < 8; ct++) {
        float v = m2[ct];
        v = fmaxf(v, __shfl_xor(v, 16, 64));
        v = fmaxf(v, __shfl_xor(v, 32, 64));
        m2[ct] = v;
    }
    // lane L stores cols L and 64+L:  col = (q or 4+q)*16 + m
    float v1 = q == 0 ? m2[0] : q == 1 ? m2[1] : q == 2 ? m2[2] : m2[3];
    float v2 = q == 0 ? m2[4] : q == 1 ? m2[5] : q == 2 ? m2[6] : m2[7];
    float* op = Ph + (size_t)blk * 128;
    op[L] = v1; op[64 + L] = v2;
}

// ---------------------------------------------------------------------------
// vn_attn: per-batch tail on folded matrices.
// All serial inner products restructured to 4 independent FMA chains;
// scores: one poly per thread (no per-p cross-lane reductions).
// ---------------------------------------------------------------------------
__global__ __launch_bounds__(256) void vn_attn(
    const float* __restrict__ data, const float* __restrict__ Ph,
    const float* __restrict__ Mff, const float* __restrict__ u0f,
    const float* __restrict__ Wvf, const float* __restrict__ bv,
    float* __restrict__ out)
{
    __shared__ __align__(16) float pah[128], tts[128], att[256], pb[128];
    __shared__ __align__(16) float part[256];
    __shared__ float red[8];
    const int b = blockIdx.x, tid = threadIdx.x, lane = tid & 63, wave = tid >> 6;
    const float* PhB = Ph + (size_t)b * NPOLY * 128;
    const int agent = (int)data[(size_t)b * NV * LCH];

    if (tid < 128) pah[tid] = PhB[(size_t)agent * 128 + tid];
    __syncthreads();

    // tts[j] = u0f[j] + sum_i pah[i]*Mff[i][j]; i-range split over 2 halves
    {
        const int j = tid & 127, h = tid >> 7;
        const float* mc = Mff + (size_t)(h * 64) * 128 + j;
        const float* pv = pah + h * 64;
        float s0 = 0.f, s1 = 0.f, s2 = 0.f, s3 = 0.f;
        for (int i = 0; i < 64; i += 4) {
            s0 = fmaf(pv[i],     mc[(i)     * 128], s0);
            s1 = fmaf(pv[i + 1], mc[(i + 1) * 128], s1);
            s2 = fmaf(pv[i + 2], mc[(i + 2) * 128], s2);
            s3 = fmaf(pv[i + 3], mc[(i + 3) * 128], s3);
        }
        part[tid] = (s0 + s1) + (s2 + s3);
    }
    __syncthreads();
    if (tid < 128) tts[tid] = part[tid] + part[128 + tid] + u0f[tid];
    __syncthreads();

    // scores: thread tid handles poly p = tid
    float sv;
    {
        const float* pr = PhB + (size_t)tid * 128;
        float s0 = 0.f, s1 = 0.f, s2 = 0.f, s3 = 0.f;
        for (int j = 0; j < 128; j += 16) {
            float4 x0 = *(const float4*)(pr + j);
            float4 x1 = *(const float4*)(pr + j + 4);
            float4 x2 = *(const float4*)(pr + j + 8);
            float4 x3 = *(const float4*)(pr + j + 12);
            float4 t0 = *(const float4*)(tts + j);
            float4 t1 = *(const float4*)(tts + j + 4);
            float4 t2 = *(const float4*)(tts + j + 8);
            float4 t3 = *(const float4*)(tts + j + 12);
            s0 = fmaf(x0.w, t0.w, fmaf(x0.z, t0.z, fmaf(x0.y, t0.y, fmaf(x0.x, t0.x, s0))));
            s1 = fmaf(x1.w, t1.w, fmaf(x1.z, t1.z, fmaf(x1.y, t1.y, fmaf(x1.x, t1.x, s1))));
            s2 = fmaf(x2.w, t2.w, fmaf(x2.z, t2.z, fmaf(x2.y, t2.y, fmaf(x2.x, t2.x, s2))));
            s3 = fmaf(x3.w, t3.w, fmaf(x3.z, t3.z, fmaf(x3.y, t3.y, fmaf(x3.x, t3.x, s3))));
        }
        sv = ((s0 + s1) + (s2 + s3)) * 0.0625f;
    }
    // softmax over 256 scores
    float mx = sv;
    #pragma unroll
    for (int s = 1; s < 64; s <<= 1) mx = fmaxf(mx, __shfl_xor(mx, s, 64));
    if (lane == 0) red[wave] = mx;
    __syncthreads();
    mx = fmaxf(fmaxf(red[0], red[1]), fmaxf(red[2], red[3]));
    float e = expf(sv - mx);
    float sm = e;
    #pragma unroll
    for (int s = 1; s < 64; s <<= 1) sm += __shfl_xor(sm, s, 64);
    if (lane == 0) red[4 + wave] = sm;
    __syncthreads();
    const float tot = red[4] + red[5] + red[6] + red[7];
    att[tid] = e / tot;
    __syncthreads();

    // pb[c] = sum_p att[p]*PhB[p][c]; p-range split over 2 halves
    {
        const int c = tid & 127, h = tid >> 7;
        const float* pp = PhB + (size_t)(h * 128) * 128 + c;
        const float* ap = att + h * 128;
        float s0 = 0.f, s1 = 0.f, s2 = 0.f, s3 = 0.f;
        for (int p = 0; p < 128; p += 4) {
            s0 = fmaf(ap[p],     pp[(p)     * 128], s0);
            s1 = fmaf(ap[p + 1], pp[(p + 1) * 128], s1);
            s2 = fmaf(ap[p + 2], pp[(p + 2) * 128], s2);
            s3 = fmaf(ap[p + 3], pp[(p + 3) * 128], s3);
        }
        part[tid] = (s0 + s1) + (s2 + s3);
    }
    __syncthreads();
    if (tid < 128) pb[tid] = part[tid] + part[128 + tid];
    __syncthreads();

    // out[c] = bv[c] + sum_j pb[j]*Wvf[j][c]
    {
        const float* wv = Wvf + tid;
        float s0 = 0.f, s1 = 0.f, s2 = 0.f, s3 = 0.f;
        for (int j = 0; j < 128; j += 4) {
            s0 = fmaf(pb[j],     wv[(j)     * 256], s0);
            s1 = fmaf(pb[j + 1], wv[(j + 1) * 256], s1);
            s2 = fmaf(pb[j + 2], wv[(j + 2) * 256], s2);
            s3 = fmaf(pb[j + 3], wv[(j + 3) * 256], s3);
        }
        out[(size_t)b * 256 + tid] = bv[tid] + ((s0 + s1) + (s2 + s3));
    }
}

extern "C" void kernel_launch(void* const* d_in, const int* in_sizes, int n_in,
                              void* d_out, int out_size, void* d_ws, size_t ws_size,
                              hipStream_t stream)
{
    const float* data = (const float*)d_in[0];
    const float* W0 = (const float*)d_in[1];
    const float* b0 = (const float*)d_in[2];
    const float* g0 = (const float*)d_in[3];
    const float* be0= (const float*)d_in[4];
    const float* W1 = (const float*)d_in[5];
    const float* b1 = (const float*)d_in[6];
    const float* g1 = (const float*)d_in[7];
    const float* be1= (const float*)d_in[8];
    const float* W2 = (const float*)d_in[9];
    const float* b2 = (const float*)d_in[10];
    const float* g2 = (const float*)d_in[11];
    const float* be2= (const float*)d_in[12];
    const float* Wq = (const float*)d_in[13];
    const float* bq = (const float*)d_in[14];
    const float* Wk = (const float*)d_in[15];
    const float* bk = (const float*)d_in[16];
    const float* Wv = (const float*)d_in[17];
    const float* bv = (const float*)d_in[18];
    (void)bk;

    char* wsb = (char*)d_ws;
    float* Ph    = (float*)(wsb);                  // 4 MB
    float* Wqf   = (float*)(wsb + 4194304);        // 128 KB
    float* Wkf   = (float*)(wsb + 4325376);        // 128 KB
    float* Wvf   = (float*)(wsb + 4456448);        // 128 KB
    float* Mff   = (float*)(wsb + 4587520);        // 64 KB
    float* u0f   = (float*)(wsb + 4653056);        // 512 B
    uint4* wpack = (uint4*)(wsb + 4653568);        // 22 KB

    vn_prep1<<<390, 256, 0, stream>>>(W0, W1, W2, Wq, Wk, Wv, Wqf, Wkf, Wvf, wpack);
    vn_prep2<<<65, 256, 0, stream>>>(Wqf, Wkf, bq, Mff, u0f);
    vn_mlp<<<32 * NPOLY, 64, 0, stream>>>(data, wpack,
                                          b0, g0, be0,
                                          W1, b1, g1, be1,
                                          W2, b2, g2, be2, Ph);
    vn_attn<<<32, 256, 0, stream>>>(data, Ph, Mff, u0f, Wvf, bv, (float*)d_out);
}

// Round 3
// 209.837 us; speedup vs baseline: 1.2035x; 1.1157x over previous
//
#include <hip/hip_runtime.h>

#define NPOLY 256
#define VPP   64
#define LCH   32
#define NV    (1 + NPOLY * VPP)
#define LN_EPS 1e-5f

typedef __bf16 bf16x8 __attribute__((ext_vector_type(8)));
typedef float  f32x4  __attribute__((ext_vector_type(4)));

union U4B8 { uint4 u; bf16x8 v; };

// hardware RNE pack: lo=bf16(a), hi=bf16(b)
__device__ __forceinline__ unsigned packbf(float a, float b) {
    unsigned r;
    asm("v_cvt_pk_bf16_f32 %0, %1, %2" : "=v"(r) : "v"(a), "v"(b));
    return r;
}

// ---------------------------------------------------------------------------
// prep1: (a) fold Wq/Wk/Wv over the duplicated 128-channel halves of P,
//        (b) pack W0 / W1-top / W2-top into bf16 B-fragment order:
//        frag f, lane L: 8 bf16 = W[k0 + j][ct*16 + (L&15)], k0 = (L>>4)*8 (+ks*32)
// ---------------------------------------------------------------------------
__global__ void vn_prep1(const float* __restrict__ W0, const float* __restrict__ W1,
                         const float* __restrict__ W2,
                         const float* __restrict__ Wq, const float* __restrict__ Wk,
                         const float* __restrict__ Wv,
                         float* __restrict__ Wqf, float* __restrict__ Wkf,
                         float* __restrict__ Wvf, uint4* __restrict__ wpack)
{
    int t = blockIdx.x * 256 + threadIdx.x;
    if (t < 3 * 32768) {
        int which = t >> 15, r = t & 32767;    // r = i*256+c, i<128
        const float* src = which == 0 ? Wq : which == 1 ? Wk : Wv;
        float*       dst = which == 0 ? Wqf : which == 1 ? Wkf : Wvf;
        dst[r] = src[r] + src[r + 128 * 256];
        return;
    }
    t -= 3 * 32768;
    if (t >= 22 * 64) return;
    int f = t >> 6, L = t & 63, q = L >> 4, m = L & 15;
    const float* src; int N, k0, col;
    if (f < 2)      { src = W0; N = 32;  k0 = q * 8;                 col = f * 16 + m; }
    else if (f < 6) { src = W1; N = 64;  k0 = q * 8;                 col = (f - 2) * 16 + m; }
    else { int g = f - 6; src = W2; N = 128; k0 = (g >> 3) * 32 + q * 8; col = (g & 7) * 16 + m; }
    float e[8];
    #pragma unroll
    for (int j = 0; j < 8; j++) e[j] = src[(k0 + j) * N + col];
    uint4 o;
    o.x = packbf(e[0], e[1]); o.y = packbf(e[2], e[3]);
    o.z = packbf(e[4], e[5]); o.w = packbf(e[6], e[7]);
    wpack[f * 64 + L] = o;
}

// ---------------------------------------------------------------------------
// prep2: Mff[i][j] = sum_c Wqf[i][c] * Wkf[j][c]   (128x128, K=256)
//        u0f[j]    = sum_c bq[c]    * Wkf[j][c]
// ---------------------------------------------------------------------------
__global__ void vn_prep2(const float* __restrict__ Wqf, const float* __restrict__ Wkf,
                         const float* __restrict__ bq,
                         float* __restrict__ Mff, float* __restrict__ u0f)
{
    int t = blockIdx.x * 256 + threadIdx.x;
    if (t < 16384) {
        int i = t >> 7, j = t & 127;
        const float4* a = (const float4*)(Wqf + i * 256);
        const float4* b = (const float4*)(Wkf + j * 256);
        float s0 = 0.f, s1 = 0.f, s2 = 0.f, s3 = 0.f;
        #pragma unroll 4
        for (int c = 0; c < 64; c++) {
            float4 A = a[c], B = b[c];
            s0 = fmaf(A.x, B.x, s0); s1 = fmaf(A.y, B.y, s1);
            s2 = fmaf(A.z, B.z, s2); s3 = fmaf(A.w, B.w, s3);
        }
        Mff[i * 128 + j] = (s0 + s1) + (s2 + s3);
    } else if (t < 16512) {
        int j = t - 16384;
        const float4* a = (const float4*)bq;
        const float4* b = (const float4*)(Wkf + j * 256);
        float s0 = 0.f, s1 = 0.f, s2 = 0.f, s3 = 0.f;
        #pragma unroll 4
        for (int c = 0; c < 64; c++) {
            float4 A = a[c], B = b[c];
            s0 = fmaf(A.x, B.x, s0); s1 = fmaf(A.y, B.y, s1);
            s2 = fmaf(A.z, B.z, s2); s3 = fmaf(A.w, B.w, s3);
        }
        u0f[j] = (s0 + s1) + (s2 + s3);
    }
}

// ---------------------------------------------------------------------------
// vn_mlp v3: ONE POLY PER 256-THREAD BLOCK, 4 waves x 16 rows each.
// Per-wave register footprint ~4x smaller than the 1-wave/poly version
// (layer2 single-pass acc2[8] = 32 regs) -> no spill, no recompute pass,
// 4-5 blocks/CU occupancy.
// LN is per-row -> fully wave-local. Cross-wave traffic is only:
//   partA: per-wave column-max partials, partB: per-wave au-FMA partials,
//   combined after __syncthreads (5 per block).
// C/D layout (m89): col = lane&15, row = (lane>>4)*4 + reg.
// A layout (m120): A[m = lane&15][k = (lane>>4)*8 + j].
// ---------------------------------------------------------------------------
__global__ __launch_bounds__(256, 3) void vn_mlp(
    const float* __restrict__ data, const uint4* __restrict__ wpack,
    const float* __restrict__ b0, const float* __restrict__ g0, const float* __restrict__ be0,
    const float* __restrict__ W1, const float* __restrict__ b1,
    const float* __restrict__ g1, const float* __restrict__ be1,
    const float* __restrict__ W2, const float* __restrict__ b2,
    const float* __restrict__ g2, const float* __restrict__ be2,
    float* __restrict__ Ph)
{
    __shared__ __align__(16) unsigned short hbuf[64 * 72];  // 9216 B (rows wave-owned)
    __shared__ float partA[4][128];   // per-wave column-max partials
    __shared__ float partB[4][128];   // per-wave au partials

    const int tid = threadIdx.x;
    const int w = tid >> 6, L = tid & 63, q = L >> 4, m = L & 15;
    const int blk = blockIdx.x;
    const int bb = blk >> 8, pp = blk & 255;
    const int r0 = w * 16;            // this wave's row base

    // ---------------- layer 0 : 32 -> 32 (rows r0..r0+15) ----------------
    const float* rowbase = data + ((size_t)bb * NV + 1 + (size_t)pp * VPP) * LCH;
    bf16x8 A0;
    {
        const float* rp = rowbase + (size_t)(r0 + m) * LCH + q * 8;
        float4 u = *(const float4*)rp;
        float4 v = *(const float4*)(rp + 4);
        if (q == 3) v.w = 0.f;                 // vecs[:, :, -1] = 0
        U4B8 c;
        c.u.x = packbf(u.x, u.y); c.u.y = packbf(u.z, u.w);
        c.u.z = packbf(v.x, v.y); c.u.w = packbf(v.z, v.w);
        A0 = c.v;
    }
    f32x4 acc0[2];
    {
        U4B8 t0, t1; t0.u = wpack[0 * 64 + L]; t1.u = wpack[1 * 64 + L];
        float bca = b0[m], bcb = b0[16 + m];
        f32x4 a0 = { bca, bca, bca, bca };
        f32x4 a1 = { bcb, bcb, bcb, bcb };
        acc0[0] = __builtin_amdgcn_mfma_f32_16x16x32_bf16(A0, t0.v, a0, 0, 0, 0);
        acc0[1] = __builtin_amdgcn_mfma_f32_16x16x32_bf16(A0, t1.v, a1, 0, 0, 0);
    }
    // LN (per row, N=32) + relu + wave-partial col-max
    {
        float g0c[2]  = { g0[m],  g0[16 + m]  };
        float be0c[2] = { be0[m], be0[16 + m] };
        float a0mx[2] = { 0.f, 0.f };
        #pragma unroll
        for (int reg = 0; reg < 4; reg++) {
            float x0 = acc0[0][reg], x1 = acc0[1][reg];
            float rs = x0 + x1, rq = x0 * x0 + x1 * x1;
            #pragma unroll
            for (int s = 1; s < 16; s <<= 1) { rs += __shfl_xor(rs, s, 64); rq += __shfl_xor(rq, s, 64); }
            float mu = rs * (1.f / 32.f);
            float var = rq * (1.f / 32.f) - mu * mu;
            float ri = rsqrtf(var + LN_EPS);
            #pragma unroll
            for (int ct = 0; ct < 2; ct++) {
                float v = fmaxf(fmaf(g0c[ct] * ri, acc0[ct][reg] - mu, be0c[ct]), 0.f);
                acc0[ct][reg] = v;
                a0mx[ct] = fmaxf(a0mx[ct], v);
            }
        }
        #pragma unroll
        for (int ct = 0; ct < 2; ct++) {
            float v = a0mx[ct];
            v = fmaxf(v, __shfl_xor(v, 16, 64));
            v = fmaxf(v, __shfl_xor(v, 32, 64));
            a0mx[ct] = v;
        }
        if (q == 0) { partA[w][m] = a0mx[0]; partA[w][16 + m] = a0mx[1]; }
    }
    // stage h0 (bf16) for layer-1 A fragments (wave-local rows)
    #pragma unroll
    for (int reg = 0; reg < 4; reg++) {
        int row = r0 + q * 4 + reg;
        unsigned u = packbf(acc0[0][reg], acc0[1][reg]);
        hbuf[row * 72 + m]      = (unsigned short)u;
        hbuf[row * 72 + 16 + m] = (unsigned short)(u >> 16);
    }
    __syncthreads();   // (1) partA ready

    // au1 partial: wave w covers j = w*8 .. w*8+7
    {
        float p = 0.f;
        int j0 = w * 8;
        #pragma unroll
        for (int jj = 0; jj < 8; jj++) {
            int j = j0 + jj;
            float a = fmaxf(fmaxf(partA[0][j], partA[1][j]), fmaxf(partA[2][j], partA[3][j]));
            p = fmaf(a, W1[(32 + j) * 64 + L], p);
        }
        partB[w][L] = p;
    }
    __syncthreads();   // (2) partB(au1) ready

    // ---------------- layer 1 : 64(per-row 32) -> 64 ----------------
    bf16x8 A1;
    { U4B8 c; c.u = *(const uint4*)(hbuf + (r0 + m) * 72 + q * 8); A1 = c.v; }
    f32x4 acc1[4];
    #pragma unroll
    for (int ct = 0; ct < 4; ct++) {
        U4B8 wv; wv.u = wpack[(2 + ct) * 64 + L];
        int n = ct * 16 + m;
        float au = b1[n] + ((partB[0][n] + partB[1][n]) + (partB[2][n] + partB[3][n]));
        f32x4 a = { au, au, au, au };
        acc1[ct] = __builtin_amdgcn_mfma_f32_16x16x32_bf16(A1, wv.v, a, 0, 0, 0);
    }
    {
        float g1c[4], be1c[4];
        #pragma unroll
        for (int ct = 0; ct < 4; ct++) { g1c[ct] = g1[ct * 16 + m]; be1c[ct] = be1[ct * 16 + m]; }
        float a1mx[4] = { 0.f, 0.f, 0.f, 0.f };
        #pragma unroll
        for (int reg = 0; reg < 4; reg++) {
            float rs = 0.f, rq = 0.f;
            #pragma unroll
            for (int ct = 0; ct < 4; ct++) { float x = acc1[ct][reg]; rs += x; rq += x * x; }
            #pragma unroll
            for (int s = 1; s < 16; s <<= 1) { rs += __shfl_xor(rs, s, 64); rq += __shfl_xor(rq, s, 64); }
            float mu = rs * (1.f / 64.f);
            float var = rq * (1.f / 64.f) - mu * mu;
            float ri = rsqrtf(var + LN_EPS);
            #pragma unroll
            for (int ct = 0; ct < 4; ct++) {
                float v = fmaxf(fmaf(g1c[ct] * ri, acc1[ct][reg] - mu, be1c[ct]), 0.f);
                acc1[ct][reg] = v;
                a1mx[ct] = fmaxf(a1mx[ct], v);
            }
        }
        #pragma unroll
        for (int ct = 0; ct < 4; ct++) {
            float v = a1mx[ct];
            v = fmaxf(v, __shfl_xor(v, 16, 64));
            v = fmaxf(v, __shfl_xor(v, 32, 64));
            a1mx[ct] = v;
        }
        if (q == 0) {
            #pragma unroll
            for (int ct = 0; ct < 4; ct++) partA[w][ct * 16 + m] = a1mx[ct];
        }
    }
    // stage h1 (bf16), wave-local rows
    #pragma unroll
    for (int reg = 0; reg < 4; reg++) {
        int row = r0 + q * 4 + reg;
        unsigned ua = packbf(acc1[0][reg], acc1[1][reg]);
        unsigned ub = packbf(acc1[2][reg], acc1[3][reg]);
        hbuf[row * 72 + m]      = (unsigned short)ua;
        hbuf[row * 72 + 16 + m] = (unsigned short)(ua >> 16);
        hbuf[row * 72 + 32 + m] = (unsigned short)ub;
        hbuf[row * 72 + 48 + m] = (unsigned short)(ub >> 16);
    }
    __syncthreads();   // (3) partA(l1 colmax) ready

    // au2 partial: wave w covers j = w*16 .. w*16+15; outputs cols L and 64+L
    {
        float pa = 0.f, pb = 0.f;
        int j0 = w * 16;
        #pragma unroll
        for (int jj = 0; jj < 16; jj++) {
            int j = j0 + jj;
            float a = fmaxf(fmaxf(partA[0][j], partA[1][j]), fmaxf(partA[2][j], partA[3][j]));
            pa = fmaf(a, W2[(64 + j) * 128 + L],      pa);
            pb = fmaf(a, W2[(64 + j) * 128 + 64 + L], pb);
        }
        partB[w][L]      = pa;
        partB[w][64 + L] = pb;
    }
    __syncthreads();   // (4) partB(au2) ready

    // ---------------- layer 2 : 128(per-row 64) -> 128, single pass ----------------
    bf16x8 A2[2];
    #pragma unroll
    for (int ks = 0; ks < 2; ks++) {
        U4B8 c; c.u = *(const uint4*)(hbuf + (r0 + m) * 72 + ks * 32 + q * 8);
        A2[ks] = c.v;
    }
    f32x4 acc2[8];
    #pragma unroll
    for (int ct = 0; ct < 8; ct++) {
        U4B8 wa, wb;
        wa.u = wpack[(6 + ct) * 64 + L];
        wb.u = wpack[(14 + ct) * 64 + L];
        int n = ct * 16 + m;
        float au = b2[n] + ((partB[0][n] + partB[1][n]) + (partB[2][n] + partB[3][n]));
        f32x4 a = { au, au, au, au };
        a = __builtin_amdgcn_mfma_f32_16x16x32_bf16(A2[0], wa.v, a, 0, 0, 0);
        a = __builtin_amdgcn_mfma_f32_16x16x32_bf16(A2[1], wb.v, a, 0, 0, 0);
        acc2[ct] = a;
    }
    {
        float g2c[8], be2c[8];
        #pragma unroll
        for (int ct = 0; ct < 8; ct++) { g2c[ct] = g2[ct * 16 + m]; be2c[ct] = be2[ct * 16 + m]; }
        float m2[8] = { 0.f, 0.f, 0.f, 0.f, 0.f, 0.f, 0.f, 0.f };
        #pragma unroll
        for (int reg = 0; reg < 4; reg++) {
            float rs = 0.f, rq = 0.f;
            #pragma unroll
            for (int ct = 0; ct < 8; ct++) { float x = acc2[ct][reg]; rs += x; rq += x * x; }
            #pragma unroll
            for (int s = 1; s < 16; s <<= 1) { rs += __shfl_xor(rs, s, 64); rq += __shfl_xor(rq, s, 64); }
            float mu = rs * (1.f / 128.f);
            float var = rq * (1.f / 128.f) - mu * mu;
            float ri = rsqrtf(var + LN_EPS);
            #pragma unroll
            for (int ct = 0; ct < 8; ct++) {
                float v = fmaxf(fmaf(g2c[ct] * ri, acc2[ct][reg] - mu, be2c[ct]), 0.f);
                m2[ct] = fmaxf(m2[ct], v);
            }
        }
        #pragma unroll
        for (int ct = 0; ct < 8; ct++) {
            float v = m2[ct];
            v = fmaxf(v, __shfl_xor(v, 16, 64));
            v = fmaxf(v, __shfl_xor(v, 32, 64));
            m2[ct] = v;
        }
        if (q == 0) {
            #pragma unroll
            for (int ct = 0; ct < 8; ct++) partA[w][ct * 16 + m] = m2[ct];
        }
    }
    __syncthreads();   // (5) partA(l2 colmax) ready

    if (tid < 128) {
        float v = fmaxf(fmaxf(partA[0][tid], partA[1][tid]),
                        fmaxf(partA[2][tid], partA[3][tid]));
        Ph[(size_t)blk * 128 + tid] = v;
    }
}

// ---------------------------------------------------------------------------
// vn_attn: per-batch tail on folded matrices (unchanged from round 2).
// ---------------------------------------------------------------------------
__global__ __launch_bounds__(256) void vn_attn(
    const float* __restrict__ data, const float* __restrict__ Ph,
    const float* __restrict__ Mff, const float* __restrict__ u0f,
    const float* __restrict__ Wvf, const float* __restrict__ bv,
    float* __restrict__ out)
{
    __shared__ __align__(16) float pah[128], tts[128], att[256], pb[128];
    __shared__ __align__(16) float part[256];
    __shared__ float red[8];
    const int b = blockIdx.x, tid = threadIdx.x, lane = tid & 63, wave = tid >> 6;
    const float* PhB = Ph + (size_t)b * NPOLY * 128;
    const int agent = (int)data[(size_t)b * NV * LCH];

    if (tid < 128) pah[tid] = PhB[(size_t)agent * 128 + tid];
    __syncthreads();

    // tts[j] = u0f[j] + sum_i pah[i]*Mff[i][j]; i-range split over 2 halves
    {
        const int j = tid & 127, h = tid >> 7;
        const float* mc = Mff + (size_t)(h * 64) * 128 + j;
        const float* pv = pah + h * 64;
        float s0 = 0.f, s1 = 0.f, s2 = 0.f, s3 = 0.f;
        for (int i = 0; i < 64; i += 4) {
            s0 = fmaf(pv[i],     mc[(i)     * 128], s0);
            s1 = fmaf(pv[i + 1], mc[(i + 1) * 128], s1);
            s2 = fmaf(pv[i + 2], mc[(i + 2) * 128], s2);
            s3 = fmaf(pv[i + 3], mc[(i + 3) * 128], s3);
        }
        part[tid] = (s0 + s1) + (s2 + s3);
    }
    __syncthreads();
    if (tid < 128) tts[tid] = part[tid] + part[128 + tid] + u0f[tid];
    __syncthreads();

    // scores: thread tid handles poly p = tid
    float sv;
    {
        const float* pr = PhB + (size_t)tid * 128;
        float s0 = 0.f, s1 = 0.f, s2 = 0.f, s3 = 0.f;
        for (int j = 0; j < 128; j += 16) {
            float4 x0 = *(const float4*)(pr + j);
            float4 x1 = *(const float4*)(pr + j + 4);
            float4 x2 = *(const float4*)(pr + j + 8);
            float4 x3 = *(const float4*)(pr + j + 12);
            float4 t0 = *(const float4*)(tts + j);
            float4 t1 = *(const float4*)(tts + j + 4);
            float4 t2 = *(const float4*)(tts + j + 8);
            float4 t3 = *(const float4*)(tts + j + 12);
            s0 = fmaf(x0.w, t0.w, fmaf(x0.z, t0.z, fmaf(x0.y, t0.y, fmaf(x0.x, t0.x, s0))));
            s1 = fmaf(x1.w, t1.w, fmaf(x1.z, t1.z, fmaf(x1.y, t1.y, fmaf(x1.x, t1.x, s1))));
            s2 = fmaf(x2.w, t2.w, fmaf(x2.z, t2.z, fmaf(x2.y, t2.y, fmaf(x2.x, t2.x, s2))));
            s3 = fmaf(x3.w, t3.w, fmaf(x3.z, t3.z, fmaf(x3.y, t3.y, fmaf(x3.x, t3.x, s3))));
        }
        sv = ((s0 + s1) + (s2 + s3)) * 0.0625f;
    }
    // softmax over 256 scores
    float mx = sv;
    #pragma unroll
    for (int s = 1; s < 64; s <<= 1) mx = fmaxf(mx, __shfl_xor(mx, s, 64));
    if (lane == 0) red[wave] = mx;
    __syncthreads();
    mx = fmaxf(fmaxf(red[0], red[1]), fmaxf(red[2], red[3]));
    float e = expf(sv - mx);
    float sm = e;
    #pragma unroll
    for (int s = 1; s < 64; s <<= 1) sm += __shfl_xor(sm, s, 64);
    if (lane == 0) red[4 + wave] = sm;
    __syncthreads();
    const float tot = red[4] + red[5] + red[6] + red[7];
    att[tid] = e / tot;
    __syncthreads();

    // pb[c] = sum_p att[p]*PhB[p][c]; p-range split over 2 halves
    {
        const int c = tid & 127, h = tid >> 7;
        const float* pp = PhB + (size_t)(h * 128) * 128 + c;
        const float* ap = att + h * 128;
        float s0 = 0.f, s1 = 0.f, s2 = 0.f, s3 = 0.f;
        for (int p = 0; p < 128; p += 4) {
            s0 = fmaf(ap[p],     pp[(p)     * 128], s0);
            s1 = fmaf(ap[p + 1], pp[(p + 1) * 128], s1);
            s2 = fmaf(ap[p + 2], pp[(p + 2) * 128], s2);
            s3 = fmaf(ap[p + 3], pp[(p + 3) * 128], s3);
        }
        part[tid] = (s0 + s1) + (s2 + s3);
    }
    __syncthreads();
    if (tid < 128) pb[tid] = part[tid] + part[128 + tid];
    __syncthreads();

    // out[c] = bv[c] + sum_j pb[j]*Wvf[j][c]
    {
        const float* wv = Wvf + tid;
        float s0 = 0.f, s1 = 0.f, s2 = 0.f, s3 = 0.f;
        for (int j = 0; j < 128; j += 4) {
            s0 = fmaf(pb[j],     wv[(j)     * 256], s0);
            s1 = fmaf(pb[j + 1], wv[(j + 1) * 256], s1);
            s2 = fmaf(pb[j + 2], wv[(j + 2) * 256], s2);
            s3 = fmaf(pb[j + 3], wv[(j + 3) * 256], s3);
        }
        out[(size_t)b * 256 + tid] = bv[tid] + ((s0 + s1) + (s2 + s3));
    }
}

extern "C" void kernel_launch(void* const* d_in, const int* in_sizes, int n_in,
                              void* d_out, int out_size, void* d_ws, size_t ws_size,
                              hipStream_t stream)
{
    const float* data = (const float*)d_in[0];
    const float* W0 = (const float*)d_in[1];
    const float* b0 = (const float*)d_in[2];
    const float* g0 = (const float*)d_in[3];
    const float* be0= (const float*)d_in[4];
    const float* W1 = (const float*)d_in[5];
    const float* b1 = (const float*)d_in[6];
    const float* g1 = (const float*)d_in[7];
    const float* be1= (const float*)d_in[8];
    const float* W2 = (const float*)d_in[9];
    const float* b2 = (const float*)d_in[10];
    const float* g2 = (const float*)d_in[11];
    const float* be2= (const float*)d_in[12];
    const float* Wq = (const float*)d_in[13];
    const float* bq = (const float*)d_in[14];
    const float* Wk = (const float*)d_in[15];
    const float* bk = (const float*)d_in[16];
    const float* Wv = (const float*)d_in[17];
    const float* bv = (const float*)d_in[18];
    (void)bk;

    char* wsb = (char*)d_ws;
    float* Ph    = (float*)(wsb);                  // 4 MB
    float* Wqf   = (float*)(wsb + 4194304);        // 128 KB
    float* Wkf   = (float*)(wsb + 4325376);        // 128 KB
    float* Wvf   = (float*)(wsb + 4456448);        // 128 KB
    float* Mff   = (float*)(wsb + 4587520);        // 64 KB
    float* u0f   = (float*)(wsb + 4653056);        // 512 B
    uint4* wpack = (uint4*)(wsb + 4653568);        // 22 KB

    vn_prep1<<<390, 256, 0, stream>>>(W0, W1, W2, Wq, Wk, Wv, Wqf, Wkf, Wvf, wpack);
    vn_prep2<<<65, 256, 0, stream>>>(Wqf, Wkf, bq, Mff, u0f);
    vn_mlp<<<32 * NPOLY, 256, 0, stream>>>(data, wpack,
                                           b0, g0, be0,
                                           W1, b1, g1, be1,
                                           W2, b2, g2, be2, Ph);
    vn_attn<<<32, 256, 0, stream>>>(data, Ph, Mff, u0f, Wvf, bv, (float*)d_out);
}

// Round 4
// 204.721 us; speedup vs baseline: 1.2336x; 1.0250x over previous
//
#include <hip/hip_runtime.h>

#define NPOLY 256
#define VPP   64
#define LCH   32
#define NV    (1 + NPOLY * VPP)
#define LN_EPS 1e-5f

typedef __bf16 bf16x8 __attribute__((ext_vector_type(8)));
typedef float  f32x4  __attribute__((ext_vector_type(4)));

union U4B8 { uint4 u; bf16x8 v; };

// hardware RNE pack: lo=bf16(a), hi=bf16(b)
__device__ __forceinline__ unsigned packbf(float a, float b) {
    unsigned r;
    asm("v_cvt_pk_bf16_f32 %0, %1, %2" : "=v"(r) : "v"(a), "v"(b));
    return r;
}

// DPP cross-lane term (VALU-only, fuses to v_add_f32_dpp; no DS op, no lgkmcnt)
#define DPPF(x, ctrl) __int_as_float(__builtin_amdgcn_update_dpp(0, __float_as_int(x), (ctrl), 0xF, 0xF, true))

// 16-lane butterfly sum (bitwise == __shfl_xor 1/2/4/8 tree):
// quad_perm[1,0,3,2]=0xB1 (xor1), quad_perm[2,3,0,1]=0x4E (xor2),
// row_half_mirror=0x141 (xor7 -> other quad), row_mirror=0x140 (xor15 -> other 8-group)
__device__ __forceinline__ float red16sum(float x) {
    x += DPPF(x, 0xB1);
    x += DPPF(x, 0x4E);
    x += DPPF(x, 0x141);
    x += DPPF(x, 0x140);
    return x;
}

// ---------------------------------------------------------------------------
// vn_prep (merged): one kernel, independent ranges.
//  [0, 32768)        : fold Wv -> Wvf
//  [32768, 34176)    : pack W0 / W1-top / W2-top into bf16 B-fragment order
//  [34176, 50560)    : Mff[i][j] = sum_c (Wq[i][c]+Wq[i+128][c])(Wk[j][c]+Wk[j+128][c])
//  [50560, 50688)    : u0f[j]    = sum_c bq[c]*(Wk[j][c]+Wk[j+128][c])
// ---------------------------------------------------------------------------
__global__ void vn_prep(const float* __restrict__ W0, const float* __restrict__ W1,
                        const float* __restrict__ W2,
                        const float* __restrict__ Wq, const float* __restrict__ Wk,
                        const float* __restrict__ Wv, const float* __restrict__ bq,
                        float* __restrict__ Wvf, uint4* __restrict__ wpack,
                        float* __restrict__ Mff, float* __restrict__ u0f)
{
    int t = blockIdx.x * 256 + threadIdx.x;
    if (t < 32768) {                     // Wv fold
        Wvf[t] = Wv[t] + Wv[t + 128 * 256];
        return;
    }
    t -= 32768;
    if (t < 22 * 64) {                   // wpack
        int f = t >> 6, L = t & 63, q = L >> 4, m = L & 15;
        const float* src; int N, k0, col;
        if (f < 2)      { src = W0; N = 32;  k0 = q * 8;                 col = f * 16 + m; }
        else if (f < 6) { src = W1; N = 64;  k0 = q * 8;                 col = (f - 2) * 16 + m; }
        else { int g = f - 6; src = W2; N = 128; k0 = (g >> 3) * 32 + q * 8; col = (g & 7) * 16 + m; }
        float e[8];
        #pragma unroll
        for (int j = 0; j < 8; j++) e[j] = src[(k0 + j) * N + col];
        uint4 o;
        o.x = packbf(e[0], e[1]); o.y = packbf(e[2], e[3]);
        o.z = packbf(e[4], e[5]); o.w = packbf(e[6], e[7]);
        wpack[f * 64 + L] = o;
        return;
    }
    t -= 22 * 64;
    if (t < 16384) {                     // Mff with inline fold
        int i = t >> 7, j = t & 127;
        const float4* q0 = (const float4*)(Wq + (size_t)i * 256);
        const float4* q1 = (const float4*)(Wq + (size_t)(i + 128) * 256);
        const float4* k0 = (const float4*)(Wk + (size_t)j * 256);
        const float4* k1 = (const float4*)(Wk + (size_t)(j + 128) * 256);
        float s0 = 0.f, s1 = 0.f, s2 = 0.f, s3 = 0.f;
        #pragma unroll 4
        for (int c = 0; c < 64; c++) {
            float4 A0 = q0[c], A1 = q1[c], B0 = k0[c], B1 = k1[c];
            s0 = fmaf(A0.x + A1.x, B0.x + B1.x, s0);
            s1 = fmaf(A0.y + A1.y, B0.y + B1.y, s1);
            s2 = fmaf(A0.z + A1.z, B0.z + B1.z, s2);
            s3 = fmaf(A0.w + A1.w, B0.w + B1.w, s3);
        }
        Mff[i * 128 + j] = (s0 + s1) + (s2 + s3);
        return;
    }
    t -= 16384;
    if (t < 128) {                       // u0f with inline fold
        int j = t;
        const float4* a  = (const float4*)bq;
        const float4* k0 = (const float4*)(Wk + (size_t)j * 256);
        const float4* k1 = (const float4*)(Wk + (size_t)(j + 128) * 256);
        float s0 = 0.f, s1 = 0.f, s2 = 0.f, s3 = 0.f;
        #pragma unroll 4
        for (int c = 0; c < 64; c++) {
            float4 A = a[c]; float4 B0 = k0[c], B1 = k1[c];
            s0 = fmaf(A.x, B0.x + B1.x, s0);
            s1 = fmaf(A.y, B0.y + B1.y, s1);
            s2 = fmaf(A.z, B0.z + B1.z, s2);
            s3 = fmaf(A.w, B0.w + B1.w, s3);
        }
        u0f[j] = (s0 + s1) + (s2 + s3);
    }
}

// ---------------------------------------------------------------------------
// vn_mlp: ONE POLY PER 256-THREAD BLOCK, 4 waves x 16 rows each.
// LN row-reductions via DPP butterfly (red16sum) - VALU-only, no DS traffic.
// C/D layout (m89): col = lane&15, row = (lane>>4)*4 + reg.
// A layout (m120): A[m = lane&15][k = (lane>>4)*8 + j].
// ---------------------------------------------------------------------------
__global__ __launch_bounds__(256, 3) void vn_mlp(
    const float* __restrict__ data, const uint4* __restrict__ wpack,
    const float* __restrict__ b0, const float* __restrict__ g0, const float* __restrict__ be0,
    const float* __restrict__ W1, const float* __restrict__ b1,
    const float* __restrict__ g1, const float* __restrict__ be1,
    const float* __restrict__ W2, const float* __restrict__ b2,
    const float* __restrict__ g2, const float* __restrict__ be2,
    float* __restrict__ Ph)
{
    __shared__ __align__(16) unsigned short hbuf[64 * 72];  // 9216 B (rows wave-owned)
    __shared__ float partA[4][128];   // per-wave column-max partials
    __shared__ float partB[4][128];   // per-wave au partials

    const int tid = threadIdx.x;
    const int w = tid >> 6, L = tid & 63, q = L >> 4, m = L & 15;
    const int blk = blockIdx.x;
    const int bb = blk >> 8, pp = blk & 255;
    const int r0 = w * 16;            // this wave's row base

    // ---------------- layer 0 : 32 -> 32 (rows r0..r0+15) ----------------
    const float* rowbase = data + ((size_t)bb * NV + 1 + (size_t)pp * VPP) * LCH;
    bf16x8 A0;
    {
        const float* rp = rowbase + (size_t)(r0 + m) * LCH + q * 8;
        float4 u = *(const float4*)rp;
        float4 v = *(const float4*)(rp + 4);
        if (q == 3) v.w = 0.f;                 // vecs[:, :, -1] = 0
        U4B8 c;
        c.u.x = packbf(u.x, u.y); c.u.y = packbf(u.z, u.w);
        c.u.z = packbf(v.x, v.y); c.u.w = packbf(v.z, v.w);
        A0 = c.v;
    }
    f32x4 acc0[2];
    {
        U4B8 t0, t1; t0.u = wpack[0 * 64 + L]; t1.u = wpack[1 * 64 + L];
        float bca = b0[m], bcb = b0[16 + m];
        f32x4 a0 = { bca, bca, bca, bca };
        f32x4 a1 = { bcb, bcb, bcb, bcb };
        acc0[0] = __builtin_amdgcn_mfma_f32_16x16x32_bf16(A0, t0.v, a0, 0, 0, 0);
        acc0[1] = __builtin_amdgcn_mfma_f32_16x16x32_bf16(A0, t1.v, a1, 0, 0, 0);
    }
    // LN (per row, N=32) + relu + wave-partial col-max
    {
        float g0c[2]  = { g0[m],  g0[16 + m]  };
        float be0c[2] = { be0[m], be0[16 + m] };
        float a0mx[2] = { 0.f, 0.f };
        #pragma unroll
        for (int reg = 0; reg < 4; reg++) {
            float x0 = acc0[0][reg], x1 = acc0[1][reg];
            float rs = red16sum(x0 + x1);
            float rq = red16sum(x0 * x0 + x1 * x1);
            float mu = rs * (1.f / 32.f);
            float var = rq * (1.f / 32.f) - mu * mu;
            float ri = rsqrtf(var + LN_EPS);
            #pragma unroll
            for (int ct = 0; ct < 2; ct++) {
                float v = fmaxf(fmaf(g0c[ct] * ri, acc0[ct][reg] - mu, be0c[ct]), 0.f);
                acc0[ct][reg] = v;
                a0mx[ct] = fmaxf(a0mx[ct], v);
            }
        }
        #pragma unroll
        for (int ct = 0; ct < 2; ct++) {
            float v = a0mx[ct];
            v = fmaxf(v, __shfl_xor(v, 16, 64));
            v = fmaxf(v, __shfl_xor(v, 32, 64));
            a0mx[ct] = v;
        }
        if (q == 0) { partA[w][m] = a0mx[0]; partA[w][16 + m] = a0mx[1]; }
    }
    // stage h0 (bf16) for layer-1 A fragments (wave-local rows)
    #pragma unroll
    for (int reg = 0; reg < 4; reg++) {
        int row = r0 + q * 4 + reg;
        unsigned u = packbf(acc0[0][reg], acc0[1][reg]);
        hbuf[row * 72 + m]      = (unsigned short)u;
        hbuf[row * 72 + 16 + m] = (unsigned short)(u >> 16);
    }
    __syncthreads();   // (1) partA ready

    // au1 partial: wave w covers j = w*8 .. w*8+7
    {
        float p = 0.f;
        int j0 = w * 8;
        #pragma unroll
        for (int jj = 0; jj < 8; jj++) {
            int j = j0 + jj;
            float a = fmaxf(fmaxf(partA[0][j], partA[1][j]), fmaxf(partA[2][j], partA[3][j]));
            p = fmaf(a, W1[(32 + j) * 64 + L], p);
        }
        partB[w][L] = p;
    }
    __syncthreads();   // (2) partB(au1) ready

    // ---------------- layer 1 : 64(per-row 32) -> 64 ----------------
    bf16x8 A1;
    { U4B8 c; c.u = *(const uint4*)(hbuf + (r0 + m) * 72 + q * 8); A1 = c.v; }
    f32x4 acc1[4];
    #pragma unroll
    for (int ct = 0; ct < 4; ct++) {
        U4B8 wv; wv.u = wpack[(2 + ct) * 64 + L];
        int n = ct * 16 + m;
        float au = b1[n] + ((partB[0][n] + partB[1][n]) + (partB[2][n] + partB[3][n]));
        f32x4 a = { au, au, au, au };
        acc1[ct] = __builtin_amdgcn_mfma_f32_16x16x32_bf16(A1, wv.v, a, 0, 0, 0);
    }
    {
        float g1c[4], be1c[4];
        #pragma unroll
        for (int ct = 0; ct < 4; ct++) { g1c[ct] = g1[ct * 16 + m]; be1c[ct] = be1[ct * 16 + m]; }
        float a1mx[4] = { 0.f, 0.f, 0.f, 0.f };
        #pragma unroll
        for (int reg = 0; reg < 4; reg++) {
            float rs = 0.f, rq = 0.f;
            #pragma unroll
            for (int ct = 0; ct < 4; ct++) { float x = acc1[ct][reg]; rs += x; rq = fmaf(x, x, rq); }
            rs = red16sum(rs);
            rq = red16sum(rq);
            float mu = rs * (1.f / 64.f);
            float var = rq * (1.f / 64.f) - mu * mu;
            float ri = rsqrtf(var + LN_EPS);
            #pragma unroll
            for (int ct = 0; ct < 4; ct++) {
                float v = fmaxf(fmaf(g1c[ct] * ri, acc1[ct][reg] - mu, be1c[ct]), 0.f);
                acc1[ct][reg] = v;
                a1mx[ct] = fmaxf(a1mx[ct], v);
            }
        }
        #pragma unroll
        for (int ct = 0; ct < 4; ct++) {
            float v = a1mx[ct];
            v = fmaxf(v, __shfl_xor(v, 16, 64));
            v = fmaxf(v, __shfl_xor(v, 32, 64));
            a1mx[ct] = v;
        }
        if (q == 0) {
            #pragma unroll
            for (int ct = 0; ct < 4; ct++) partA[w][ct * 16 + m] = a1mx[ct];
        }
    }
    // stage h1 (bf16), wave-local rows
    #pragma unroll
    for (int reg = 0; reg < 4; reg++) {
        int row = r0 + q * 4 + reg;
        unsigned ua = packbf(acc1[0][reg], acc1[1][reg]);
        unsigned ub = packbf(acc1[2][reg], acc1[3][reg]);
        hbuf[row * 72 + m]      = (unsigned short)ua;
        hbuf[row * 72 + 16 + m] = (unsigned short)(ua >> 16);
        hbuf[row * 72 + 32 + m] = (unsigned short)ub;
        hbuf[row * 72 + 48 + m] = (unsigned short)(ub >> 16);
    }
    __syncthreads();   // (3) partA(l1 colmax) ready

    // au2 partial: wave w covers j = w*16 .. w*16+15; outputs cols L and 64+L
    {
        float pa = 0.f, pb = 0.f;
        int j0 = w * 16;
        #pragma unroll
        for (int jj = 0; jj < 16; jj++) {
            int j = j0 + jj;
            float a = fmaxf(fmaxf(partA[0][j], partA[1][j]), fmaxf(partA[2][j], partA[3][j]));
            pa = fmaf(a, W2[(64 + j) * 128 + L],      pa);
            pb = fmaf(a, W2[(64 + j) * 128 + 64 + L], pb);
        }
        partB[w][L]      = pa;
        partB[w][64 + L] = pb;
    }
    __syncthreads();   // (4) partB(au2) ready

    // ---------------- layer 2 : 128(per-row 64) -> 128, single pass ----------------
    bf16x8 A2[2];
    #pragma unroll
    for (int ks = 0; ks < 2; ks++) {
        U4B8 c; c.u = *(const uint4*)(hbuf + (r0 + m) * 72 + ks * 32 + q * 8);
        A2[ks] = c.v;
    }
    f32x4 acc2[8];
    #pragma unroll
    for (int ct = 0; ct < 8; ct++) {
        U4B8 wa, wb;
        wa.u = wpack[(6 + ct) * 64 + L];
        wb.u = wpack[(14 + ct) * 64 + L];
        int n = ct * 16 + m;
        float au = b2[n] + ((partB[0][n] + partB[1][n]) + (partB[2][n] + partB[3][n]));
        f32x4 a = { au, au, au, au };
        a = __builtin_amdgcn_mfma_f32_16x16x32_bf16(A2[0], wa.v, a, 0, 0, 0);
        a = __builtin_amdgcn_mfma_f32_16x16x32_bf16(A2[1], wb.v, a, 0, 0, 0);
        acc2[ct] = a;
    }
    {
        float g2c[8], be2c[8];
        #pragma unroll
        for (int ct = 0; ct < 8; ct++) { g2c[ct] = g2[ct * 16 + m]; be2c[ct] = be2[ct * 16 + m]; }
        float m2[8] = { 0.f, 0.f, 0.f, 0.f, 0.f, 0.f, 0.f, 0.f };
        #pragma unroll
        for (int reg = 0; reg < 4; reg++) {
            float rs = 0.f, rq = 0.f;
            #pragma unroll
            for (int ct = 0; ct < 8; ct++) { float x = acc2[ct][reg]; rs += x; rq = fmaf(x, x, rq); }
            rs = red16sum(rs);
            rq = red16sum(rq);
            float mu = rs * (1.f / 128.f);
            float var = rq * (1.f / 128.f) - mu * mu;
            float ri = rsqrtf(var + LN_EPS);
            #pragma unroll
            for (int ct = 0; ct < 8; ct++) {
                float v = fmaxf(fmaf(g2c[ct] * ri, acc2[ct][reg] - mu, be2c[ct]), 0.f);
                m2[ct] = fmaxf(m2[ct], v);
            }
        }
        #pragma unroll
        for (int ct = 0; ct < 8; ct++) {
            float v = m2[ct];
            v = fmaxf(v, __shfl_xor(v, 16, 64));
            v = fmaxf(v, __shfl_xor(v, 32, 64));
            m2[ct] = v;
        }
        if (q == 0) {
            #pragma unroll
            for (int ct = 0; ct < 8; ct++) partA[w][ct * 16 + m] = m2[ct];
        }
    }
    __syncthreads();   // (5) partA(l2 colmax) ready

    if (tid < 128) {
        float v = fmaxf(fmaxf(partA[0][tid], partA[1][tid]),
                        fmaxf(partA[2][tid], partA[3][tid]));
        Ph[(size_t)blk * 128 + tid] = v;
    }
}

// ---------------------------------------------------------------------------
// vn_attn: per-batch tail. Ph block (128 KB) staged ONCE into LDS with a
// 129-float row pitch (conflict-free row reads in scores, col reads in pb).
// Global reads: Ph once coalesced + Mff/Wvf coalesced. All loops unrolled.
// ---------------------------------------------------------------------------
__global__ __launch_bounds__(256) void vn_attn(
    const float* __restrict__ data, const float* __restrict__ Ph,
    const float* __restrict__ Mff, const float* __restrict__ u0f,
    const float* __restrict__ Wvf, const float* __restrict__ bv,
    float* __restrict__ out)
{
    extern __shared__ float shPh[];                 // [256][129] = 132096 B
    __shared__ __align__(16) float pah[128], tts[128], att[256], pb[128];
    __shared__ __align__(16) float part[256];
    __shared__ float red[8];
    const int b = blockIdx.x, tid = threadIdx.x, lane = tid & 63, wave = tid >> 6;
    const float* PhB = Ph + (size_t)b * NPOLY * 128;
    const int agent = (int)data[(size_t)b * NV * LCH];

    if (tid < 128) pah[tid] = PhB[(size_t)agent * 128 + tid];
    // stage PhB -> shPh (pitch 129)
    {
        const float4* src = (const float4*)PhB;
        #pragma unroll
        for (int it = 0; it < 32; it++) {
            int idx4 = it * 256 + tid;              // 8192 float4 total
            float4 v = src[idx4];
            int lin = idx4 * 4;
            int p = lin >> 7, c = lin & 127;
            float* dst = shPh + p * 129 + c;
            dst[0] = v.x; dst[1] = v.y; dst[2] = v.z; dst[3] = v.w;
        }
    }
    __syncthreads();

    // tts[j] = u0f[j] + sum_i pah[i]*Mff[i][j]; i-range split over 2 halves
    {
        const int j = tid & 127, h = tid >> 7;
        const float* mc = Mff + (size_t)(h * 64) * 128 + j;
        const float* pv = pah + h * 64;
        float s0 = 0.f, s1 = 0.f, s2 = 0.f, s3 = 0.f;
        #pragma unroll
        for (int i = 0; i < 64; i += 4) {
            s0 = fmaf(pv[i],     mc[(i)     * 128], s0);
            s1 = fmaf(pv[i + 1], mc[(i + 1) * 128], s1);
            s2 = fmaf(pv[i + 2], mc[(i + 2) * 128], s2);
            s3 = fmaf(pv[i + 3], mc[(i + 3) * 128], s3);
        }
        part[tid] = (s0 + s1) + (s2 + s3);
    }
    __syncthreads();
    if (tid < 128) tts[tid] = part[tid] + part[128 + tid] + u0f[tid];
    __syncthreads();

    // scores: thread tid handles poly p = tid, row read from LDS (bank-clean)
    float sv;
    {
        const float* prl = shPh + tid * 129;
        float s0 = 0.f, s1 = 0.f, s2 = 0.f, s3 = 0.f;
        #pragma unroll
        for (int j = 0; j < 128; j += 4) {
            s0 = fmaf(prl[j],     tts[j],     s0);
            s1 = fmaf(prl[j + 1], tts[j + 1], s1);
            s2 = fmaf(prl[j + 2], tts[j + 2], s2);
            s3 = fmaf(prl[j + 3], tts[j + 3], s3);
        }
        sv = ((s0 + s1) + (s2 + s3)) * 0.0625f;
    }
    // softmax over 256 scores
    float mx = sv;
    #pragma unroll
    for (int s = 1; s < 64; s <<= 1) mx = fmaxf(mx, __shfl_xor(mx, s, 64));
    if (lane == 0) red[wave] = mx;
    __syncthreads();
    mx = fmaxf(fmaxf(red[0], red[1]), fmaxf(red[2], red[3]));
    float e = expf(sv - mx);
    float sm = e;
    #pragma unroll
    for (int s = 1; s < 64; s <<= 1) sm += __shfl_xor(sm, s, 64);
    if (lane == 0) red[4 + wave] = sm;
    __syncthreads();
    const float tot = red[4] + red[5] + red[6] + red[7];
    att[tid] = e / tot;
    __syncthreads();

    // pb[c] = sum_p att[p]*shPh[p][c]; p-range split over 2 halves
    {
        const int c = tid & 127, h = tid >> 7;
        const float* ap = att + h * 128;
        const float* pp = shPh + (size_t)(h * 128) * 129 + c;
        float s0 = 0.f, s1 = 0.f, s2 = 0.f, s3 = 0.f;
        #pragma unroll
        for (int p = 0; p < 128; p += 4) {
            s0 = fmaf(ap[p],     pp[(p)     * 129], s0);
            s1 = fmaf(ap[p + 1], pp[(p + 1) * 129], s1);
            s2 = fmaf(ap[p + 2], pp[(p + 2) * 129], s2);
            s3 = fmaf(ap[p + 3], pp[(p + 3) * 129], s3);
        }
        part[tid] = (s0 + s1) + (s2 + s3);
    }
    __syncthreads();
    if (tid < 128) pb[tid] = part[tid] + part[128 + tid];
    __syncthreads();

    // out[c] = bv[c] + sum_j pb[j]*Wvf[j][c]
    {
        const float* wv = Wvf + tid;
        float s0 = 0.f, s1 = 0.f, s2 = 0.f, s3 = 0.f;
        #pragma unroll
        for (int j = 0; j < 128; j += 4) {
            s0 = fmaf(pb[j],     wv[(j)     * 256], s0);
            s1 = fmaf(pb[j + 1], wv[(j + 1) * 256], s1);
            s2 = fmaf(pb[j + 2], wv[(j + 2) * 256], s2);
            s3 = fmaf(pb[j + 3], wv[(j + 3) * 256], s3);
        }
        out[(size_t)b * 256 + tid] = bv[tid] + ((s0 + s1) + (s2 + s3));
    }
}

extern "C" void kernel_launch(void* const* d_in, const int* in_sizes, int n_in,
                              void* d_out, int out_size, void* d_ws, size_t ws_size,
                              hipStream_t stream)
{
    const float* data = (const float*)d_in[0];
    const float* W0 = (const float*)d_in[1];
    const float* b0 = (const float*)d_in[2];
    const float* g0 = (const float*)d_in[3];
    const float* be0= (const float*)d_in[4];
    const float* W1 = (const float*)d_in[5];
    const float* b1 = (const float*)d_in[6];
    const float* g1 = (const float*)d_in[7];
    const float* be1= (const float*)d_in[8];
    const float* W2 = (const float*)d_in[9];
    const float* b2 = (const float*)d_in[10];
    const float* g2 = (const float*)d_in[11];
    const float* be2= (const float*)d_in[12];
    const float* Wq = (const float*)d_in[13];
    const float* bq = (const float*)d_in[14];
    const float* Wk = (const float*)d_in[15];
    const float* bk = (const float*)d_in[16];
    const float* Wv = (const float*)d_in[17];
    const float* bv = (const float*)d_in[18];
    (void)bk;

    char* wsb = (char*)d_ws;
    float* Ph    = (float*)(wsb);                  // 4 MB
    float* Wvf   = (float*)(wsb + 4456448);        // 128 KB
    float* Mff   = (float*)(wsb + 4587520);        // 64 KB
    float* u0f   = (float*)(wsb + 4653056);        // 512 B
    uint4* wpack = (uint4*)(wsb + 4653568);        // 22 KB

    static int attn_attr_set = 0;
    if (!attn_attr_set) {
        hipFuncSetAttribute((const void*)vn_attn,
                            hipFuncAttributeMaxDynamicSharedMemorySize, 132096);
        attn_attr_set = 1;
    }

    vn_prep<<<198, 256, 0, stream>>>(W0, W1, W2, Wq, Wk, Wv, bq, Wvf, wpack, Mff, u0f);
    vn_mlp<<<32 * NPOLY, 256, 0, stream>>>(data, wpack,
                                           b0, g0, be0,
                                           W1, b1, g1, be1,
                                           W2, b2, g2, be2, Ph);
    vn_attn<<<32, 256, 132096, stream>>>(data, Ph, Mff, u0f, Wvf, bv, (float*)d_out);
}

// Round 5
// 189.858 us; speedup vs baseline: 1.3302x; 1.0783x over previous
//
#include <hip/hip_runtime.h>

#define NPOLY 256
#define VPP   64
#define LCH   32
#define NV    (1 + NPOLY * VPP)
#define LN_EPS 1e-5f

typedef __bf16 bf16x8 __attribute__((ext_vector_type(8)));
typedef float  f32x4  __attribute__((ext_vector_type(4)));

union U4B8 { uint4 u; bf16x8 v; };

// hardware RNE pack: lo=bf16(a), hi=bf16(b)
__device__ __forceinline__ unsigned packbf(float a, float b) {
    unsigned r;
    asm("v_cvt_pk_bf16_f32 %0, %1, %2" : "=v"(r) : "v"(a), "v"(b));
    return r;
}

// DPP cross-lane term (VALU-only, fuses to v_add_f32_dpp; no DS op, no lgkmcnt)
#define DPPF(x, ctrl) __int_as_float(__builtin_amdgcn_update_dpp(0, __float_as_int(x), (ctrl), 0xF, 0xF, true))

// 16-lane butterfly sum (bitwise == __shfl_xor 1/2/4/8 tree)
__device__ __forceinline__ float red16sum(float x) {
    x += DPPF(x, 0xB1);
    x += DPPF(x, 0x4E);
    x += DPPF(x, 0x141);
    x += DPPF(x, 0x140);
    return x;
}

// ---------------------------------------------------------------------------
// vn_prep: pure coalesced folds, NO Mff matmul (eliminated algebraically).
//  [0, 32768)      : Wvf[r]  = Wv[r] + Wv[r+32768]
//  [32768, 65536)  : Wqf[r]  = Wq[r] + Wq[r+32768]
//  [65536, 98304)  : WkfT[c*128+j] = Wk[j*256+c] + Wk[(j+128)*256+c]
//                    (coalesced read over c; scattered 4B writes, 128 KB total)
//  [98304, 99712)  : pack W0 / W1-top / W2-top into bf16 B-fragment order
// ---------------------------------------------------------------------------
__global__ void vn_prep(const float* __restrict__ W0, const float* __restrict__ W1,
                        const float* __restrict__ W2,
                        const float* __restrict__ Wq, const float* __restrict__ Wk,
                        const float* __restrict__ Wv,
                        float* __restrict__ Wvf, float* __restrict__ Wqf,
                        float* __restrict__ WkfT, uint4* __restrict__ wpack)
{
    int t = blockIdx.x * 256 + threadIdx.x;
    if (t < 32768) {                     // Wv fold
        Wvf[t] = Wv[t] + Wv[t + 32768];
        return;
    }
    t -= 32768;
    if (t < 32768) {                     // Wq fold
        Wqf[t] = Wq[t] + Wq[t + 32768];
        return;
    }
    t -= 32768;
    if (t < 32768) {                     // Wk fold + transpose
        int j = t >> 8, c = t & 255;
        WkfT[c * 128 + j] = Wk[j * 256 + c] + Wk[(j + 128) * 256 + c];
        return;
    }
    t -= 32768;
    if (t < 22 * 64) {                   // wpack
        int f = t >> 6, L = t & 63, q = L >> 4, m = L & 15;
        const float* src; int N, k0, col;
        if (f < 2)      { src = W0; N = 32;  k0 = q * 8;                 col = f * 16 + m; }
        else if (f < 6) { src = W1; N = 64;  k0 = q * 8;                 col = (f - 2) * 16 + m; }
        else { int g = f - 6; src = W2; N = 128; k0 = (g >> 3) * 32 + q * 8; col = (g & 7) * 16 + m; }
        float e[8];
        #pragma unroll
        for (int j = 0; j < 8; j++) e[j] = src[(k0 + j) * N + col];
        uint4 o;
        o.x = packbf(e[0], e[1]); o.y = packbf(e[2], e[3]);
        o.z = packbf(e[4], e[5]); o.w = packbf(e[6], e[7]);
        wpack[f * 64 + L] = o;
    }
}

// ---------------------------------------------------------------------------
// vn_mlp: ONE POLY PER 256-THREAD BLOCK, 4 waves x 16 rows each (unchanged
// from round 4 -- VALU-issue-bound at ~85% busy).
// ---------------------------------------------------------------------------
__global__ __launch_bounds__(256, 3) void vn_mlp(
    const float* __restrict__ data, const uint4* __restrict__ wpack,
    const float* __restrict__ b0, const float* __restrict__ g0, const float* __restrict__ be0,
    const float* __restrict__ W1, const float* __restrict__ b1,
    const float* __restrict__ g1, const float* __restrict__ be1,
    const float* __restrict__ W2, const float* __restrict__ b2,
    const float* __restrict__ g2, const float* __restrict__ be2,
    float* __restrict__ Ph)
{
    __shared__ __align__(16) unsigned short hbuf[64 * 72];  // 9216 B (rows wave-owned)
    __shared__ float partA[4][128];   // per-wave column-max partials
    __shared__ float partB[4][128];   // per-wave au partials

    const int tid = threadIdx.x;
    const int w = tid >> 6, L = tid & 63, q = L >> 4, m = L & 15;
    const int blk = blockIdx.x;
    const int bb = blk >> 8, pp = blk & 255;
    const int r0 = w * 16;            // this wave's row base

    // ---------------- layer 0 : 32 -> 32 (rows r0..r0+15) ----------------
    const float* rowbase = data + ((size_t)bb * NV + 1 + (size_t)pp * VPP) * LCH;
    bf16x8 A0;
    {
        const float* rp = rowbase + (size_t)(r0 + m) * LCH + q * 8;
        float4 u = *(const float4*)rp;
        float4 v = *(const float4*)(rp + 4);
        if (q == 3) v.w = 0.f;                 // vecs[:, :, -1] = 0
        U4B8 c;
        c.u.x = packbf(u.x, u.y); c.u.y = packbf(u.z, u.w);
        c.u.z = packbf(v.x, v.y); c.u.w = packbf(v.z, v.w);
        A0 = c.v;
    }
    f32x4 acc0[2];
    {
        U4B8 t0, t1; t0.u = wpack[0 * 64 + L]; t1.u = wpack[1 * 64 + L];
        float bca = b0[m], bcb = b0[16 + m];
        f32x4 a0 = { bca, bca, bca, bca };
        f32x4 a1 = { bcb, bcb, bcb, bcb };
        acc0[0] = __builtin_amdgcn_mfma_f32_16x16x32_bf16(A0, t0.v, a0, 0, 0, 0);
        acc0[1] = __builtin_amdgcn_mfma_f32_16x16x32_bf16(A0, t1.v, a1, 0, 0, 0);
    }
    // LN (per row, N=32) + relu + wave-partial col-max
    {
        float g0c[2]  = { g0[m],  g0[16 + m]  };
        float be0c[2] = { be0[m], be0[16 + m] };
        float a0mx[2] = { 0.f, 0.f };
        #pragma unroll
        for (int reg = 0; reg < 4; reg++) {
            float x0 = acc0[0][reg], x1 = acc0[1][reg];
            float rs = red16sum(x0 + x1);
            float rq = red16sum(x0 * x0 + x1 * x1);
            float mu = rs * (1.f / 32.f);
            float var = rq * (1.f / 32.f) - mu * mu;
            float ri = rsqrtf(var + LN_EPS);
            #pragma unroll
            for (int ct = 0; ct < 2; ct++) {
                float v = fmaxf(fmaf(g0c[ct] * ri, acc0[ct][reg] - mu, be0c[ct]), 0.f);
                acc0[ct][reg] = v;
                a0mx[ct] = fmaxf(a0mx[ct], v);
            }
        }
        #pragma unroll
        for (int ct = 0; ct < 2; ct++) {
            float v = a0mx[ct];
            v = fmaxf(v, __shfl_xor(v, 16, 64));
            v = fmaxf(v, __shfl_xor(v, 32, 64));
            a0mx[ct] = v;
        }
        if (q == 0) { partA[w][m] = a0mx[0]; partA[w][16 + m] = a0mx[1]; }
    }
    // stage h0 (bf16) for layer-1 A fragments (wave-local rows)
    #pragma unroll
    for (int reg = 0; reg < 4; reg++) {
        int row = r0 + q * 4 + reg;
        unsigned u = packbf(acc0[0][reg], acc0[1][reg]);
        hbuf[row * 72 + m]      = (unsigned short)u;
        hbuf[row * 72 + 16 + m] = (unsigned short)(u >> 16);
    }
    __syncthreads();   // (1) partA ready

    // au1 partial: wave w covers j = w*8 .. w*8+7
    {
        float p = 0.f;
        int j0 = w * 8;
        #pragma unroll
        for (int jj = 0; jj < 8; jj++) {
            int j = j0 + jj;
            float a = fmaxf(fmaxf(partA[0][j], partA[1][j]), fmaxf(partA[2][j], partA[3][j]));
            p = fmaf(a, W1[(32 + j) * 64 + L], p);
        }
        partB[w][L] = p;
    }
    __syncthreads();   // (2) partB(au1) ready

    // ---------------- layer 1 : 64(per-row 32) -> 64 ----------------
    bf16x8 A1;
    { U4B8 c; c.u = *(const uint4*)(hbuf + (r0 + m) * 72 + q * 8); A1 = c.v; }
    f32x4 acc1[4];
    #pragma unroll
    for (int ct = 0; ct < 4; ct++) {
        U4B8 wv; wv.u = wpack[(2 + ct) * 64 + L];
        int n = ct * 16 + m;
        float au = b1[n] + ((partB[0][n] + partB[1][n]) + (partB[2][n] + partB[3][n]));
        f32x4 a = { au, au, au, au };
        acc1[ct] = __builtin_amdgcn_mfma_f32_16x16x32_bf16(A1, wv.v, a, 0, 0, 0);
    }
    {
        float g1c[4], be1c[4];
        #pragma unroll
        for (int ct = 0; ct < 4; ct++) { g1c[ct] = g1[ct * 16 + m]; be1c[ct] = be1[ct * 16 + m]; }
        float a1mx[4] = { 0.f, 0.f, 0.f, 0.f };
        #pragma unroll
        for (int reg = 0; reg < 4; reg++) {
            float rs = 0.f, rq = 0.f;
            #pragma unroll
            for (int ct = 0; ct < 4; ct++) { float x = acc1[ct][reg]; rs += x; rq = fmaf(x, x, rq); }
            rs = red16sum(rs);
            rq = red16sum(rq);
            float mu = rs * (1.f / 64.f);
            float var = rq * (1.f / 64.f) - mu * mu;
            float ri = rsqrtf(var + LN_EPS);
            #pragma unroll
            for (int ct = 0; ct < 4; ct++) {
                float v = fmaxf(fmaf(g1c[ct] * ri, acc1[ct][reg] - mu, be1c[ct]), 0.f);
                acc1[ct][reg] = v;
                a1mx[ct] = fmaxf(a1mx[ct], v);
            }
        }
        #pragma unroll
        for (int ct = 0; ct < 4; ct++) {
            float v = a1mx[ct];
            v = fmaxf(v, __shfl_xor(v, 16, 64));
            v = fmaxf(v, __shfl_xor(v, 32, 64));
            a1mx[ct] = v;
        }
        if (q == 0) {
            #pragma unroll
            for (int ct = 0; ct < 4; ct++) partA[w][ct * 16 + m] = a1mx[ct];
        }
    }
    // stage h1 (bf16), wave-local rows
    #pragma unroll
    for (int reg = 0; reg < 4; reg++) {
        int row = r0 + q * 4 + reg;
        unsigned ua = packbf(acc1[0][reg], acc1[1][reg]);
        unsigned ub = packbf(acc1[2][reg], acc1[3][reg]);
        hbuf[row * 72 + m]      = (unsigned short)ua;
        hbuf[row * 72 + 16 + m] = (unsigned short)(ua >> 16);
        hbuf[row * 72 + 32 + m] = (unsigned short)ub;
        hbuf[row * 72 + 48 + m] = (unsigned short)(ub >> 16);
    }
    __syncthreads();   // (3) partA(l1 colmax) ready

    // au2 partial: wave w covers j = w*16 .. w*16+15; outputs cols L and 64+L
    {
        float pa = 0.f, pb = 0.f;
        int j0 = w * 16;
        #pragma unroll
        for (int jj = 0; jj < 16; jj++) {
            int j = j0 + jj;
            float a = fmaxf(fmaxf(partA[0][j], partA[1][j]), fmaxf(partA[2][j], partA[3][j]));
            pa = fmaf(a, W2[(64 + j) * 128 + L],      pa);
            pb = fmaf(a, W2[(64 + j) * 128 + 64 + L], pb);
        }
        partB[w][L]      = pa;
        partB[w][64 + L] = pb;
    }
    __syncthreads();   // (4) partB(au2) ready

    // ---------------- layer 2 : 128(per-row 64) -> 128, single pass ----------------
    bf16x8 A2[2];
    #pragma unroll
    for (int ks = 0; ks < 2; ks++) {
        U4B8 c; c.u = *(const uint4*)(hbuf + (r0 + m) * 72 + ks * 32 + q * 8);
        A2[ks] = c.v;
    }
    f32x4 acc2[8];
    #pragma unroll
    for (int ct = 0; ct < 8; ct++) {
        U4B8 wa, wb;
        wa.u = wpack[(6 + ct) * 64 + L];
        wb.u = wpack[(14 + ct) * 64 + L];
        int n = ct * 16 + m;
        float au = b2[n] + ((partB[0][n] + partB[1][n]) + (partB[2][n] + partB[3][n]));
        f32x4 a = { au, au, au, au };
        a = __builtin_amdgcn_mfma_f32_16x16x32_bf16(A2[0], wa.v, a, 0, 0, 0);
        a = __builtin_amdgcn_mfma_f32_16x16x32_bf16(A2[1], wb.v, a, 0, 0, 0);
        acc2[ct] = a;
    }
    {
        float g2c[8], be2c[8];
        #pragma unroll
        for (int ct = 0; ct < 8; ct++) { g2c[ct] = g2[ct * 16 + m]; be2c[ct] = be2[ct * 16 + m]; }
        float m2[8] = { 0.f, 0.f, 0.f, 0.f, 0.f, 0.f, 0.f, 0.f };
        #pragma unroll
        for (int reg = 0; reg < 4; reg++) {
            float rs = 0.f, rq = 0.f;
            #pragma unroll
            for (int ct = 0; ct < 8; ct++) { float x = acc2[ct][reg]; rs += x; rq = fmaf(x, x, rq); }
            rs = red16sum(rs);
            rq = red16sum(rq);
            float mu = rs * (1.f / 128.f);
            float var = rq * (1.f / 128.f) - mu * mu;
            float ri = rsqrtf(var + LN_EPS);
            #pragma unroll
            for (int ct = 0; ct < 8; ct++) {
                float v = fmaxf(fmaf(g2c[ct] * ri, acc2[ct][reg] - mu, be2c[ct]), 0.f);
                m2[ct] = fmaxf(m2[ct], v);
            }
        }
        #pragma unroll
        for (int ct = 0; ct < 8; ct++) {
            float v = m2[ct];
            v = fmaxf(v, __shfl_xor(v, 16, 64));
            v = fmaxf(v, __shfl_xor(v, 32, 64));
            m2[ct] = v;
        }
        if (q == 0) {
            #pragma unroll
            for (int ct = 0; ct < 8; ct++) partA[w][ct * 16 + m] = m2[ct];
        }
    }
    __syncthreads();   // (5) partA(l2 colmax) ready

    if (tid < 128) {
        float v = fmaxf(fmaxf(partA[0][tid], partA[1][tid]),
                        fmaxf(partA[2][tid], partA[3][tid]));
        Ph[(size_t)blk * 128 + tid] = v;
    }
}

// ---------------------------------------------------------------------------
// vn_attn: per-batch tail, Mff-free.
//   q[c]   = bq[c] + sum_i pah[i] * Wqf[i][c]        (Wqf coalesced over c)
//   tts[j] = sum_c q[c] * WkfT[c][j]                 (WkfT coalesced over j)
//   scores = Ph . tts / 16 ; softmax ; pb = att@Ph ; out = pb@Wvf + bv
// Ph block staged once into LDS (pitch 129: conflict-free rows AND cols).
// ---------------------------------------------------------------------------
__global__ __launch_bounds__(256) void vn_attn(
    const float* __restrict__ data, const float* __restrict__ Ph,
    const float* __restrict__ Wqf, const float* __restrict__ WkfT,
    const float* __restrict__ bq,
    const float* __restrict__ Wvf, const float* __restrict__ bv,
    float* __restrict__ out)
{
    extern __shared__ float shPh[];                 // [256][129] = 132096 B
    __shared__ __align__(16) float qs[256], tts[128], att[256], pb[128];
    __shared__ __align__(16) float part[256];
    __shared__ float red[8];
    const int b = blockIdx.x, tid = threadIdx.x, lane = tid & 63, wave = tid >> 6;
    const float* PhB = Ph + (size_t)b * NPOLY * 128;
    const int agent = (int)data[(size_t)b * NV * LCH];

    // stage PhB -> shPh (pitch 129), coalesced float4 reads
    {
        const float4* src = (const float4*)PhB;
        #pragma unroll
        for (int it = 0; it < 32; it++) {
            int idx4 = it * 256 + tid;              // 8192 float4 total
            float4 v = src[idx4];
            int lin = idx4 * 4;
            int p = lin >> 7, c = lin & 127;
            float* dst = shPh + p * 129 + c;
            dst[0] = v.x; dst[1] = v.y; dst[2] = v.z; dst[3] = v.w;
        }
    }
    __syncthreads();

    // q[c] = bq[c] + sum_i pah[i]*Wqf[i][c]  (pah = agent row, LDS broadcast)
    {
        const int c = tid;
        const float* pa = shPh + agent * 129;
        float s0 = bq[c], s1 = 0.f, s2 = 0.f, s3 = 0.f;
        for (int i = 0; i < 128; i += 4) {
            s0 = fmaf(pa[i],     Wqf[(i)     * 256 + c], s0);
            s1 = fmaf(pa[i + 1], Wqf[(i + 1) * 256 + c], s1);
            s2 = fmaf(pa[i + 2], Wqf[(i + 2) * 256 + c], s2);
            s3 = fmaf(pa[i + 3], Wqf[(i + 3) * 256 + c], s3);
        }
        qs[c] = (s0 + s1) + (s2 + s3);
    }
    __syncthreads();

    // tts[j] = sum_c qs[c]*WkfT[c][j]; c-range split over 2 halves
    {
        const int j = tid & 127, h = tid >> 7;
        const float* wk = WkfT + (size_t)(h * 128) * 128 + j;
        const float* qp = qs + h * 128;
        float s0 = 0.f, s1 = 0.f, s2 = 0.f, s3 = 0.f;
        for (int c = 0; c < 128; c += 4) {
            s0 = fmaf(qp[c],     wk[(c)     * 128], s0);
            s1 = fmaf(qp[c + 1], wk[(c + 1) * 128], s1);
            s2 = fmaf(qp[c + 2], wk[(c + 2) * 128], s2);
            s3 = fmaf(qp[c + 3], wk[(c + 3) * 128], s3);
        }
        part[tid] = (s0 + s1) + (s2 + s3);
    }
    __syncthreads();
    if (tid < 128) tts[tid] = part[tid] + part[128 + tid];
    __syncthreads();

    // scores: thread tid handles poly p = tid, row read from LDS
    float sv;
    {
        const float* prl = shPh + tid * 129;
        float s0 = 0.f, s1 = 0.f, s2 = 0.f, s3 = 0.f;
        #pragma unroll
        for (int j = 0; j < 128; j += 4) {
            s0 = fmaf(prl[j],     tts[j],     s0);
            s1 = fmaf(prl[j + 1], tts[j + 1], s1);
            s2 = fmaf(prl[j + 2], tts[j + 2], s2);
            s3 = fmaf(prl[j + 3], tts[j + 3], s3);
        }
        sv = ((s0 + s1) + (s2 + s3)) * 0.0625f;
    }
    // softmax over 256 scores
    float mx = sv;
    #pragma unroll
    for (int s = 1; s < 64; s <<= 1) mx = fmaxf(mx, __shfl_xor(mx, s, 64));
    if (lane == 0) red[wave] = mx;
    __syncthreads();
    mx = fmaxf(fmaxf(red[0], red[1]), fmaxf(red[2], red[3]));
    float e = expf(sv - mx);
    float sm = e;
    #pragma unroll
    for (int s = 1; s < 64; s <<= 1) sm += __shfl_xor(sm, s, 64);
    if (lane == 0) red[4 + wave] = sm;
    __syncthreads();
    const float tot = red[4] + red[5] + red[6] + red[7];
    att[tid] = e / tot;
    __syncthreads();

    // pb[c] = sum_p att[p]*shPh[p][c]; p-range split over 2 halves
    {
        const int c = tid & 127, h = tid >> 7;
        const float* ap = att + h * 128;
        const float* pp = shPh + (size_t)(h * 128) * 129 + c;
        float s0 = 0.f, s1 = 0.f, s2 = 0.f, s3 = 0.f;
        #pragma unroll
        for (int p = 0; p < 128; p += 4) {
            s0 = fmaf(ap[p],     pp[(p)     * 129], s0);
            s1 = fmaf(ap[p + 1], pp[(p + 1) * 129], s1);
            s2 = fmaf(ap[p + 2], pp[(p + 2) * 129], s2);
            s3 = fmaf(ap[p + 3], pp[(p + 3) * 129], s3);
        }
        part[tid] = (s0 + s1) + (s2 + s3);
    }
    __syncthreads();
    if (tid < 128) pb[tid] = part[tid] + part[128 + tid];
    __syncthreads();

    // out[c] = bv[c] + sum_j pb[j]*Wvf[j][c]   (Wvf coalesced over c)
    {
        const float* wv = Wvf + tid;
        float s0 = 0.f, s1 = 0.f, s2 = 0.f, s3 = 0.f;
        #pragma unroll
        for (int j = 0; j < 128; j += 4) {
            s0 = fmaf(pb[j],     wv[(j)     * 256], s0);
            s1 = fmaf(pb[j + 1], wv[(j + 1) * 256], s1);
            s2 = fmaf(pb[j + 2], wv[(j + 2) * 256], s2);
            s3 = fmaf(pb[j + 3], wv[(j + 3) * 256], s3);
        }
        out[(size_t)b * 256 + tid] = bv[tid] + ((s0 + s1) + (s2 + s3));
    }
}

extern "C" void kernel_launch(void* const* d_in, const int* in_sizes, int n_in,
                              void* d_out, int out_size, void* d_ws, size_t ws_size,
                              hipStream_t stream)
{
    const float* data = (const float*)d_in[0];
    const float* W0 = (const float*)d_in[1];
    const float* b0 = (const float*)d_in[2];
    const float* g0 = (const float*)d_in[3];
    const float* be0= (const float*)d_in[4];
    const float* W1 = (const float*)d_in[5];
    const float* b1 = (const float*)d_in[6];
    const float* g1 = (const float*)d_in[7];
    const float* be1= (const float*)d_in[8];
    const float* W2 = (const float*)d_in[9];
    const float* b2 = (const float*)d_in[10];
    const float* g2 = (const float*)d_in[11];
    const float* be2= (const float*)d_in[12];
    const float* Wq = (const float*)d_in[13];
    const float* bq = (const float*)d_in[14];
    const float* Wk = (const float*)d_in[15];
    const float* bk = (const float*)d_in[16];
    const float* Wv = (const float*)d_in[17];
    const float* bv = (const float*)d_in[18];
    (void)bk;

    char* wsb = (char*)d_ws;
    float* Ph    = (float*)(wsb);                  // 4 MB
    float* Wqf   = (float*)(wsb + 4194304);        // 128 KB
    float* WkfT  = (float*)(wsb + 4325376);        // 128 KB
    float* Wvf   = (float*)(wsb + 4456448);        // 128 KB
    uint4* wpack = (uint4*)(wsb + 4653568);        // 22 KB

    static int attn_attr_set = 0;
    if (!attn_attr_set) {
        hipFuncSetAttribute((const void*)vn_attn,
                            hipFuncAttributeMaxDynamicSharedMemorySize, 132096);
        attn_attr_set = 1;
    }

    vn_prep<<<390, 256, 0, stream>>>(W0, W1, W2, Wq, Wk, Wv, Wvf, Wqf, WkfT, wpack);
    vn_mlp<<<32 * NPOLY, 256, 0, stream>>>(data, wpack,
                                           b0, g0, be0,
                                           W1, b1, g1, be1,
                                           W2, b2, g2, be2, Ph);
    vn_attn<<<32, 256, 132096, stream>>>(data, Ph, Wqf, WkfT, bq, Wvf, bv, (float*)d_out);
}

// Round 6
// 189.203 us; speedup vs baseline: 1.3348x; 1.0035x over previous
//
#include <hip/hip_runtime.h>

#define NPOLY 256
#define VPP   64
#define LCH   32
#define NV    (1 + NPOLY * VPP)
#define LN_EPS 1e-5f

typedef __bf16 bf16x8 __attribute__((ext_vector_type(8)));
typedef float  f32x4  __attribute__((ext_vector_type(4)));

union U4B8 { uint4 u; bf16x8 v; };

// hardware RNE pack: lo=bf16(a), hi=bf16(b)
__device__ __forceinline__ unsigned packbf(float a, float b) {
    unsigned r;
    asm("v_cvt_pk_bf16_f32 %0, %1, %2" : "=v"(r) : "v"(a), "v"(b));
    return r;
}

// DPP cross-lane term (VALU-only, fuses to v_add_f32_dpp; no DS op, no lgkmcnt)
#define DPPF(x, ctrl) __int_as_float(__builtin_amdgcn_update_dpp(0, __float_as_int(x), (ctrl), 0xF, 0xF, true))

// 16-lane butterfly sum (bitwise == __shfl_xor 1/2/4/8 tree)
__device__ __forceinline__ float red16sum(float x) {
    x += DPPF(x, 0xB1);
    x += DPPF(x, 0x4E);
    x += DPPF(x, 0x141);
    x += DPPF(x, 0x140);
    return x;
}

// ---------------------------------------------------------------------------
// vn_prep: pure coalesced folds, NO Mff matmul.
// ---------------------------------------------------------------------------
__global__ void vn_prep(const float* __restrict__ W0, const float* __restrict__ W1,
                        const float* __restrict__ W2,
                        const float* __restrict__ Wq, const float* __restrict__ Wk,
                        const float* __restrict__ Wv,
                        float* __restrict__ Wvf, float* __restrict__ Wqf,
                        float* __restrict__ WkfT, uint4* __restrict__ wpack)
{
    int t = blockIdx.x * 256 + threadIdx.x;
    if (t < 32768) {                     // Wv fold
        Wvf[t] = Wv[t] + Wv[t + 32768];
        return;
    }
    t -= 32768;
    if (t < 32768) {                     // Wq fold
        Wqf[t] = Wq[t] + Wq[t + 32768];
        return;
    }
    t -= 32768;
    if (t < 32768) {                     // Wk fold + transpose
        int j = t >> 8, c = t & 255;
        WkfT[c * 128 + j] = Wk[j * 256 + c] + Wk[(j + 128) * 256 + c];
        return;
    }
    t -= 32768;
    if (t < 22 * 64) {                   // wpack
        int f = t >> 6, L = t & 63, q = L >> 4, m = L & 15;
        const float* src; int N, k0, col;
        if (f < 2)      { src = W0; N = 32;  k0 = q * 8;                 col = f * 16 + m; }
        else if (f < 6) { src = W1; N = 64;  k0 = q * 8;                 col = (f - 2) * 16 + m; }
        else { int g = f - 6; src = W2; N = 128; k0 = (g >> 3) * 32 + q * 8; col = (g & 7) * 16 + m; }
        float e[8];
        #pragma unroll
        for (int j = 0; j < 8; j++) e[j] = src[(k0 + j) * N + col];
        uint4 o;
        o.x = packbf(e[0], e[1]); o.y = packbf(e[2], e[3]);
        o.z = packbf(e[4], e[5]); o.w = packbf(e[6], e[7]);
        wpack[f * 64 + L] = o;
    }
}

// ---------------------------------------------------------------------------
// vn_mlp: ONE POLY PER 256-THREAD BLOCK, 4 waves x 16 rows each.
// New vs r5: agg0/agg1 pre-combined max arrays (saves ~72 LDS reads +
// ~72 fmax per thread in au1/au2 at the cost of 2 extra barriers).
// ---------------------------------------------------------------------------
__global__ __launch_bounds__(256, 3) void vn_mlp(
    const float* __restrict__ data, const uint4* __restrict__ wpack,
    const float* __restrict__ b0, const float* __restrict__ g0, const float* __restrict__ be0,
    const float* __restrict__ W1, const float* __restrict__ b1,
    const float* __restrict__ g1, const float* __restrict__ be1,
    const float* __restrict__ W2, const float* __restrict__ b2,
    const float* __restrict__ g2, const float* __restrict__ be2,
    float* __restrict__ Ph)
{
    __shared__ __align__(16) unsigned short hbuf[64 * 72];  // 9216 B (rows wave-owned)
    __shared__ float partA[4][128];   // per-wave column-max partials
    __shared__ float partB[4][128];   // per-wave au partials
    __shared__ float agg0[32], agg1[64];

    const int tid = threadIdx.x;
    const int w = tid >> 6, L = tid & 63, q = L >> 4, m = L & 15;
    const int blk = blockIdx.x;
    const int bb = blk >> 8, pp = blk & 255;
    const int r0 = w * 16;            // this wave's row base

    // ---------------- layer 0 : 32 -> 32 (rows r0..r0+15) ----------------
    const float* rowbase = data + ((size_t)bb * NV + 1 + (size_t)pp * VPP) * LCH;
    bf16x8 A0;
    {
        const float* rp = rowbase + (size_t)(r0 + m) * LCH + q * 8;
        float4 u = *(const float4*)rp;
        float4 v = *(const float4*)(rp + 4);
        if (q == 3) v.w = 0.f;                 // vecs[:, :, -1] = 0
        U4B8 c;
        c.u.x = packbf(u.x, u.y); c.u.y = packbf(u.z, u.w);
        c.u.z = packbf(v.x, v.y); c.u.w = packbf(v.z, v.w);
        A0 = c.v;
    }
    f32x4 acc0[2];
    {
        U4B8 t0, t1; t0.u = wpack[0 * 64 + L]; t1.u = wpack[1 * 64 + L];
        float bca = b0[m], bcb = b0[16 + m];
        f32x4 a0 = { bca, bca, bca, bca };
        f32x4 a1 = { bcb, bcb, bcb, bcb };
        acc0[0] = __builtin_amdgcn_mfma_f32_16x16x32_bf16(A0, t0.v, a0, 0, 0, 0);
        acc0[1] = __builtin_amdgcn_mfma_f32_16x16x32_bf16(A0, t1.v, a1, 0, 0, 0);
    }
    // LN (per row, N=32) + relu + wave-partial col-max
    {
        float g0c[2]  = { g0[m],  g0[16 + m]  };
        float be0c[2] = { be0[m], be0[16 + m] };
        float a0mx[2] = { 0.f, 0.f };
        #pragma unroll
        for (int reg = 0; reg < 4; reg++) {
            float x0 = acc0[0][reg], x1 = acc0[1][reg];
            float rs = red16sum(x0 + x1);
            float rq = red16sum(x0 * x0 + x1 * x1);
            float mu = rs * (1.f / 32.f);
            float var = rq * (1.f / 32.f) - mu * mu;
            float ri = rsqrtf(var + LN_EPS);
            #pragma unroll
            for (int ct = 0; ct < 2; ct++) {
                float v = fmaxf(fmaf(g0c[ct] * ri, acc0[ct][reg] - mu, be0c[ct]), 0.f);
                acc0[ct][reg] = v;
                a0mx[ct] = fmaxf(a0mx[ct], v);
            }
        }
        #pragma unroll
        for (int ct = 0; ct < 2; ct++) {
            float v = a0mx[ct];
            v = fmaxf(v, __shfl_xor(v, 16, 64));
            v = fmaxf(v, __shfl_xor(v, 32, 64));
            a0mx[ct] = v;
        }
        if (q == 0) { partA[w][m] = a0mx[0]; partA[w][16 + m] = a0mx[1]; }
    }
    // stage h0 (bf16) for layer-1 A fragments (wave-local rows)
    #pragma unroll
    for (int reg = 0; reg < 4; reg++) {
        int row = r0 + q * 4 + reg;
        unsigned u = packbf(acc0[0][reg], acc0[1][reg]);
        hbuf[row * 72 + m]      = (unsigned short)u;
        hbuf[row * 72 + 16 + m] = (unsigned short)(u >> 16);
    }
    __syncthreads();   // (1) partA ready
    if (tid < 32)
        agg0[tid] = fmaxf(fmaxf(partA[0][tid], partA[1][tid]),
                          fmaxf(partA[2][tid], partA[3][tid]));
    __syncthreads();   // (1b) agg0 ready

    // au1 partial: wave w covers j = w*8 .. w*8+7
    {
        float p = 0.f;
        int j0 = w * 8;
        #pragma unroll
        for (int jj = 0; jj < 8; jj++) {
            int j = j0 + jj;
            p = fmaf(agg0[j], W1[(32 + j) * 64 + L], p);
        }
        partB[w][L] = p;
    }
    __syncthreads();   // (2) partB(au1) ready

    // ---------------- layer 1 : 64(per-row 32) -> 64 ----------------
    bf16x8 A1;
    { U4B8 c; c.u = *(const uint4*)(hbuf + (r0 + m) * 72 + q * 8); A1 = c.v; }
    f32x4 acc1[4];
    #pragma unroll
    for (int ct = 0; ct < 4; ct++) {
        U4B8 wv; wv.u = wpack[(2 + ct) * 64 + L];
        int n = ct * 16 + m;
        float au = b1[n] + ((partB[0][n] + partB[1][n]) + (partB[2][n] + partB[3][n]));
        f32x4 a = { au, au, au, au };
        acc1[ct] = __builtin_amdgcn_mfma_f32_16x16x32_bf16(A1, wv.v, a, 0, 0, 0);
    }
    {
        float g1c[4], be1c[4];
        #pragma unroll
        for (int ct = 0; ct < 4; ct++) { g1c[ct] = g1[ct * 16 + m]; be1c[ct] = be1[ct * 16 + m]; }
        float a1mx[4] = { 0.f, 0.f, 0.f, 0.f };
        #pragma unroll
        for (int reg = 0; reg < 4; reg++) {
            float rs = 0.f, rq = 0.f;
            #pragma unroll
            for (int ct = 0; ct < 4; ct++) { float x = acc1[ct][reg]; rs += x; rq = fmaf(x, x, rq); }
            rs = red16sum(rs);
            rq = red16sum(rq);
            float mu = rs * (1.f / 64.f);
            float var = rq * (1.f / 64.f) - mu * mu;
            float ri = rsqrtf(var + LN_EPS);
            #pragma unroll
            for (int ct = 0; ct < 4; ct++) {
                float v = fmaxf(fmaf(g1c[ct] * ri, acc1[ct][reg] - mu, be1c[ct]), 0.f);
                acc1[ct][reg] = v;
                a1mx[ct] = fmaxf(a1mx[ct], v);
            }
        }
        #pragma unroll
        for (int ct = 0; ct < 4; ct++) {
            float v = a1mx[ct];
            v = fmaxf(v, __shfl_xor(v, 16, 64));
            v = fmaxf(v, __shfl_xor(v, 32, 64));
            a1mx[ct] = v;
        }
        if (q == 0) {
            #pragma unroll
            for (int ct = 0; ct < 4; ct++) partA[w][ct * 16 + m] = a1mx[ct];
        }
    }
    // stage h1 (bf16), wave-local rows
    #pragma unroll
    for (int reg = 0; reg < 4; reg++) {
        int row = r0 + q * 4 + reg;
        unsigned ua = packbf(acc1[0][reg], acc1[1][reg]);
        unsigned ub = packbf(acc1[2][reg], acc1[3][reg]);
        hbuf[row * 72 + m]      = (unsigned short)ua;
        hbuf[row * 72 + 16 + m] = (unsigned short)(ua >> 16);
        hbuf[row * 72 + 32 + m] = (unsigned short)ub;
        hbuf[row * 72 + 48 + m] = (unsigned short)(ub >> 16);
    }
    __syncthreads();   // (3) partA(l1 colmax) ready
    if (tid < 64)
        agg1[tid] = fmaxf(fmaxf(partA[0][tid], partA[1][tid]),
                          fmaxf(partA[2][tid], partA[3][tid]));
    __syncthreads();   // (3b) agg1 ready

    // au2 partial: wave w covers j = w*16 .. w*16+15; outputs cols L and 64+L
    {
        float pa = 0.f, pb = 0.f;
        int j0 = w * 16;
        #pragma unroll
        for (int jj = 0; jj < 16; jj++) {
            int j = j0 + jj;
            float a = agg1[j];
            pa = fmaf(a, W2[(64 + j) * 128 + L],      pa);
            pb = fmaf(a, W2[(64 + j) * 128 + 64 + L], pb);
        }
        partB[w][L]      = pa;
        partB[w][64 + L] = pb;
    }
    __syncthreads();   // (4) partB(au2) ready

    // ---------------- layer 2 : 128(per-row 64) -> 128, single pass ----------------
    bf16x8 A2[2];
    #pragma unroll
    for (int ks = 0; ks < 2; ks++) {
        U4B8 c; c.u = *(const uint4*)(hbuf + (r0 + m) * 72 + ks * 32 + q * 8);
        A2[ks] = c.v;
    }
    f32x4 acc2[8];
    #pragma unroll
    for (int ct = 0; ct < 8; ct++) {
        U4B8 wa, wb;
        wa.u = wpack[(6 + ct) * 64 + L];
        wb.u = wpack[(14 + ct) * 64 + L];
        int n = ct * 16 + m;
        float au = b2[n] + ((partB[0][n] + partB[1][n]) + (partB[2][n] + partB[3][n]));
        f32x4 a = { au, au, au, au };
        a = __builtin_amdgcn_mfma_f32_16x16x32_bf16(A2[0], wa.v, a, 0, 0, 0);
        a = __builtin_amdgcn_mfma_f32_16x16x32_bf16(A2[1], wb.v, a, 0, 0, 0);
        acc2[ct] = a;
    }
    {
        float g2c[8], be2c[8];
        #pragma unroll
        for (int ct = 0; ct < 8; ct++) { g2c[ct] = g2[ct * 16 + m]; be2c[ct] = be2[ct * 16 + m]; }
        float m2[8] = { 0.f, 0.f, 0.f, 0.f, 0.f, 0.f, 0.f, 0.f };
        #pragma unroll
        for (int reg = 0; reg < 4; reg++) {
            float rs = 0.f, rq = 0.f;
            #pragma unroll
            for (int ct = 0; ct < 8; ct++) { float x = acc2[ct][reg]; rs += x; rq = fmaf(x, x, rq); }
            rs = red16sum(rs);
            rq = red16sum(rq);
            float mu = rs * (1.f / 128.f);
            float var = rq * (1.f / 128.f) - mu * mu;
            float ri = rsqrtf(var + LN_EPS);
            #pragma unroll
            for (int ct = 0; ct < 8; ct++) {
                float v = fmaxf(fmaf(g2c[ct] * ri, acc2[ct][reg] - mu, be2c[ct]), 0.f);
                m2[ct] = fmaxf(m2[ct], v);
            }
        }
        #pragma unroll
        for (int ct = 0; ct < 8; ct++) {
            float v = m2[ct];
            v = fmaxf(v, __shfl_xor(v, 16, 64));
            v = fmaxf(v, __shfl_xor(v, 32, 64));
            m2[ct] = v;
        }
        if (q == 0) {
            #pragma unroll
            for (int ct = 0; ct < 8; ct++) partA[w][ct * 16 + m] = m2[ct];
        }
    }
    __syncthreads();   // (5) partA(l2 colmax) ready

    if (tid < 128) {
        float v = fmaxf(fmaxf(partA[0][tid], partA[1][tid]),
                        fmaxf(partA[2][tid], partA[3][tid]));
        Ph[(size_t)blk * 128 + tid] = v;
    }
}

// ---------------------------------------------------------------------------
// vn_attn: grid = 32 batches x 8 col-groups = 256 blocks (1 per CU).
// Each block redundantly computes the cheap shared phases (stage, q, tts,
// scores, softmax, pb -- bit-identical fp32 in every replica) and owns 32
// output columns. 8x the CUs vs the single-block-per-batch version.
// ---------------------------------------------------------------------------
__global__ __launch_bounds__(256) void vn_attn(
    const float* __restrict__ data, const float* __restrict__ Ph,
    const float* __restrict__ Wqf, const float* __restrict__ WkfT,
    const float* __restrict__ bq,
    const float* __restrict__ Wvf, const float* __restrict__ bv,
    float* __restrict__ out)
{
    extern __shared__ float shPh[];                 // [256][129] = 132096 B
    __shared__ __align__(16) float qs[256], tts[128], att[256], pb[128];
    __shared__ __align__(16) float part[256];
    __shared__ float red[8];
    const int bg = blockIdx.x, b = bg >> 3, g = bg & 7;
    const int tid = threadIdx.x, lane = tid & 63, wave = tid >> 6;
    const float* PhB = Ph + (size_t)b * NPOLY * 128;
    const int agent = (int)data[(size_t)b * NV * LCH];

    // stage PhB -> shPh (pitch 129), coalesced float4 reads
    {
        const float4* src = (const float4*)PhB;
        #pragma unroll
        for (int it = 0; it < 32; it++) {
            int idx4 = it * 256 + tid;              // 8192 float4 total
            float4 v = src[idx4];
            int lin = idx4 * 4;
            int p = lin >> 7, c = lin & 127;
            float* dst = shPh + p * 129 + c;
            dst[0] = v.x; dst[1] = v.y; dst[2] = v.z; dst[3] = v.w;
        }
    }
    __syncthreads();

    // q[c] = bq[c] + sum_i pah[i]*Wqf[i][c]  (pah = agent row, LDS broadcast)
    {
        const int c = tid;
        const float* pa = shPh + agent * 129;
        float s0 = bq[c], s1 = 0.f, s2 = 0.f, s3 = 0.f;
        for (int i = 0; i < 128; i += 4) {
            s0 = fmaf(pa[i],     Wqf[(i)     * 256 + c], s0);
            s1 = fmaf(pa[i + 1], Wqf[(i + 1) * 256 + c], s1);
            s2 = fmaf(pa[i + 2], Wqf[(i + 2) * 256 + c], s2);
            s3 = fmaf(pa[i + 3], Wqf[(i + 3) * 256 + c], s3);
        }
        qs[c] = (s0 + s1) + (s2 + s3);
    }
    __syncthreads();

    // tts[j] = sum_c qs[c]*WkfT[c][j]; c-range split over 2 halves
    {
        const int j = tid & 127, h = tid >> 7;
        const float* wk = WkfT + (size_t)(h * 128) * 128 + j;
        const float* qp = qs + h * 128;
        float s0 = 0.f, s1 = 0.f, s2 = 0.f, s3 = 0.f;
        for (int c = 0; c < 128; c += 4) {
            s0 = fmaf(qp[c],     wk[(c)     * 128], s0);
            s1 = fmaf(qp[c + 1], wk[(c + 1) * 128], s1);
            s2 = fmaf(qp[c + 2], wk[(c + 2) * 128], s2);
            s3 = fmaf(qp[c + 3], wk[(c + 3) * 128], s3);
        }
        part[tid] = (s0 + s1) + (s2 + s3);
    }
    __syncthreads();
    if (tid < 128) tts[tid] = part[tid] + part[128 + tid];
    __syncthreads();

    // scores: thread tid handles poly p = tid, row read from LDS
    float sv;
    {
        const float* prl = shPh + tid * 129;
        float s0 = 0.f, s1 = 0.f, s2 = 0.f, s3 = 0.f;
        #pragma unroll
        for (int j = 0; j < 128; j += 4) {
            s0 = fmaf(prl[j],     tts[j],     s0);
            s1 = fmaf(prl[j + 1], tts[j + 1], s1);
            s2 = fmaf(prl[j + 2], tts[j + 2], s2);
            s3 = fmaf(prl[j + 3], tts[j + 3], s3);
        }
        sv = ((s0 + s1) + (s2 + s3)) * 0.0625f;
    }
    // softmax over 256 scores
    float mx = sv;
    #pragma unroll
    for (int s = 1; s < 64; s <<= 1) mx = fmaxf(mx, __shfl_xor(mx, s, 64));
    if (lane == 0) red[wave] = mx;
    __syncthreads();
    mx = fmaxf(fmaxf(red[0], red[1]), fmaxf(red[2], red[3]));
    float e = expf(sv - mx);
    float sm = e;
    #pragma unroll
    for (int s = 1; s < 64; s <<= 1) sm += __shfl_xor(sm, s, 64);
    if (lane == 0) red[4 + wave] = sm;
    __syncthreads();
    const float tot = red[4] + red[5] + red[6] + red[7];
    att[tid] = e / tot;
    __syncthreads();

    // pb[c] = sum_p att[p]*shPh[p][c]; p-range split over 2 halves
    {
        const int c = tid & 127, h = tid >> 7;
        const float* ap = att + h * 128;
        const float* pp = shPh + (size_t)(h * 128) * 129 + c;
        float s0 = 0.f, s1 = 0.f, s2 = 0.f, s3 = 0.f;
        #pragma unroll
        for (int p = 0; p < 128; p += 4) {
            s0 = fmaf(ap[p],     pp[(p)     * 129], s0);
            s1 = fmaf(ap[p + 1], pp[(p + 1) * 129], s1);
            s2 = fmaf(ap[p + 2], pp[(p + 2) * 129], s2);
            s3 = fmaf(ap[p + 3], pp[(p + 3) * 129], s3);
        }
        part[tid] = (s0 + s1) + (s2 + s3);
    }
    __syncthreads();
    if (tid < 128) pb[tid] = part[tid] + part[128 + tid];
    __syncthreads();

    // out cols cg = g*32 .. g*32+31; j-range split over 8 groups of 16
    {
        const int c32 = tid & 31, jg = tid >> 5;
        const float* wv = Wvf + g * 32 + c32;
        const int j0 = jg * 16;
        float s0 = 0.f, s1 = 0.f;
        #pragma unroll
        for (int jj = 0; jj < 16; jj += 2) {
            s0 = fmaf(pb[j0 + jj],     wv[(j0 + jj)     * 256], s0);
            s1 = fmaf(pb[j0 + jj + 1], wv[(j0 + jj + 1) * 256], s1);
        }
        part[tid] = s0 + s1;
    }
    __syncthreads();
    if (tid < 32) {
        float s = bv[g * 32 + tid];
        #pragma unroll
        for (int k = 0; k < 8; k++) s += part[k * 32 + tid];
        out[(size_t)b * 256 + g * 32 + tid] = s;
    }
}

extern "C" void kernel_launch(void* const* d_in, const int* in_sizes, int n_in,
                              void* d_out, int out_size, void* d_ws, size_t ws_size,
                              hipStream_t stream)
{
    const float* data = (const float*)d_in[0];
    const float* W0 = (const float*)d_in[1];
    const float* b0 = (const float*)d_in[2];
    const float* g0 = (const float*)d_in[3];
    const float* be0= (const float*)d_in[4];
    const float* W1 = (const float*)d_in[5];
    const float* b1 = (const float*)d_in[6];
    const float* g1 = (const float*)d_in[7];
    const float* be1= (const float*)d_in[8];
    const float* W2 = (const float*)d_in[9];
    const float* b2 = (const float*)d_in[10];
    const float* g2 = (const float*)d_in[11];
    const float* be2= (const float*)d_in[12];
    const float* Wq = (const float*)d_in[13];
    const float* bq = (const float*)d_in[14];
    const float* Wk = (const float*)d_in[15];
    const float* bk = (const float*)d_in[16];
    const float* Wv = (const float*)d_in[17];
    const float* bv = (const float*)d_in[18];
    (void)bk;

    char* wsb = (char*)d_ws;
    float* Ph    = (float*)(wsb);                  // 4 MB
    float* Wqf   = (float*)(wsb + 4194304);        // 128 KB
    float* WkfT  = (float*)(wsb + 4325376);        // 128 KB
    float* Wvf   = (float*)(wsb + 4456448);        // 128 KB
    uint4* wpack = (uint4*)(wsb + 4653568);        // 22 KB

    static int attn_attr_set = 0;
    if (!attn_attr_set) {
        hipFuncSetAttribute((const void*)vn_attn,
                            hipFuncAttributeMaxDynamicSharedMemorySize, 132096);
        attn_attr_set = 1;
    }

    vn_prep<<<390, 256, 0, stream>>>(W0, W1, W2, Wq, Wk, Wv, Wvf, Wqf, WkfT, wpack);
    vn_mlp<<<32 * NPOLY, 256, 0, stream>>>(data, wpack,
                                           b0, g0, be0,
                                           W1, b1, g1, be1,
                                           W2, b2, g2, be2, Ph);
    vn_attn<<<32 * 8, 256, 132096, stream>>>(data, Ph, Wqf, WkfT, bq, Wvf, bv, (float*)d_out);
}

// Round 7
// 188.417 us; speedup vs baseline: 1.3403x; 1.0042x over previous
//
#include <hip/hip_runtime.h>

#define NPOLY 256
#define VPP   64
#define LCH   32
#define NV    (1 + NPOLY * VPP)
#define LN_EPS 1e-5f

typedef __bf16 bf16x8 __attribute__((ext_vector_type(8)));
typedef float  f32x4  __attribute__((ext_vector_type(4)));

union U4B8 { uint4 u; bf16x8 v; };

// hardware RNE pack: lo=bf16(a), hi=bf16(b)
__device__ __forceinline__ unsigned packbf(float a, float b) {
    unsigned r;
    asm("v_cvt_pk_bf16_f32 %0, %1, %2" : "=v"(r) : "v"(a), "v"(b));
    return r;
}

// DPP cross-lane term (VALU-only, fuses to v_add_f32_dpp; no DS op, no lgkmcnt)
#define DPPF(x, ctrl) __int_as_float(__builtin_amdgcn_update_dpp(0, __float_as_int(x), (ctrl), 0xF, 0xF, true))

// 16-lane butterfly sum (bitwise == __shfl_xor 1/2/4/8 tree)
__device__ __forceinline__ float red16sum(float x) {
    x += DPPF(x, 0xB1);
    x += DPPF(x, 0x4E);
    x += DPPF(x, 0x141);
    x += DPPF(x, 0x140);
    return x;
}

// ---------------------------------------------------------------------------
// vn_prep: pure coalesced folds, NO Mff matmul.
// ---------------------------------------------------------------------------
__global__ void vn_prep(const float* __restrict__ W0, const float* __restrict__ W1,
                        const float* __restrict__ W2,
                        const float* __restrict__ Wq, const float* __restrict__ Wk,
                        const float* __restrict__ Wv,
                        float* __restrict__ Wvf, float* __restrict__ Wqf,
                        float* __restrict__ WkfT, uint4* __restrict__ wpack)
{
    int t = blockIdx.x * 256 + threadIdx.x;
    if (t < 32768) {                     // Wv fold
        Wvf[t] = Wv[t] + Wv[t + 32768];
        return;
    }
    t -= 32768;
    if (t < 32768) {                     // Wq fold
        Wqf[t] = Wq[t] + Wq[t + 32768];
        return;
    }
    t -= 32768;
    if (t < 32768) {                     // Wk fold + transpose
        int j = t >> 8, c = t & 255;
        WkfT[c * 128 + j] = Wk[j * 256 + c] + Wk[(j + 128) * 256 + c];
        return;
    }
    t -= 32768;
    if (t < 22 * 64) {                   // wpack
        int f = t >> 6, L = t & 63, q = L >> 4, m = L & 15;
        const float* src; int N, k0, col;
        if (f < 2)      { src = W0; N = 32;  k0 = q * 8;                 col = f * 16 + m; }
        else if (f < 6) { src = W1; N = 64;  k0 = q * 8;                 col = (f - 2) * 16 + m; }
        else { int g = f - 6; src = W2; N = 128; k0 = (g >> 3) * 32 + q * 8; col = (g & 7) * 16 + m; }
        float e[8];
        #pragma unroll
        for (int j = 0; j < 8; j++) e[j] = src[(k0 + j) * N + col];
        uint4 o;
        o.x = packbf(e[0], e[1]); o.y = packbf(e[2], e[3]);
        o.z = packbf(e[4], e[5]); o.w = packbf(e[6], e[7]);
        wpack[f * 64 + L] = o;
    }
}

// ---------------------------------------------------------------------------
// vn_mlp: ONE POLY PER 256-THREAD BLOCK, 4 waves x 16 rows each.
// (Round-5 form: round 6's agg pre-combine regressed 76->84 us; reverted.)
// ---------------------------------------------------------------------------
__global__ __launch_bounds__(256, 3) void vn_mlp(
    const float* __restrict__ data, const uint4* __restrict__ wpack,
    const float* __restrict__ b0, const float* __restrict__ g0, const float* __restrict__ be0,
    const float* __restrict__ W1, const float* __restrict__ b1,
    const float* __restrict__ g1, const float* __restrict__ be1,
    const float* __restrict__ W2, const float* __restrict__ b2,
    const float* __restrict__ g2, const float* __restrict__ be2,
    float* __restrict__ Ph)
{
    __shared__ __align__(16) unsigned short hbuf[64 * 72];  // 9216 B (rows wave-owned)
    __shared__ float partA[4][128];   // per-wave column-max partials
    __shared__ float partB[4][128];   // per-wave au partials

    const int tid = threadIdx.x;
    const int w = tid >> 6, L = tid & 63, q = L >> 4, m = L & 15;
    const int blk = blockIdx.x;
    const int bb = blk >> 8, pp = blk & 255;
    const int r0 = w * 16;            // this wave's row base

    // ---------------- layer 0 : 32 -> 32 (rows r0..r0+15) ----------------
    const float* rowbase = data + ((size_t)bb * NV + 1 + (size_t)pp * VPP) * LCH;
    bf16x8 A0;
    {
        const float* rp = rowbase + (size_t)(r0 + m) * LCH + q * 8;
        float4 u = *(const float4*)rp;
        float4 v = *(const float4*)(rp + 4);
        if (q == 3) v.w = 0.f;                 // vecs[:, :, -1] = 0
        U4B8 c;
        c.u.x = packbf(u.x, u.y); c.u.y = packbf(u.z, u.w);
        c.u.z = packbf(v.x, v.y); c.u.w = packbf(v.z, v.w);
        A0 = c.v;
    }
    f32x4 acc0[2];
    {
        U4B8 t0, t1; t0.u = wpack[0 * 64 + L]; t1.u = wpack[1 * 64 + L];
        float bca = b0[m], bcb = b0[16 + m];
        f32x4 a0 = { bca, bca, bca, bca };
        f32x4 a1 = { bcb, bcb, bcb, bcb };
        acc0[0] = __builtin_amdgcn_mfma_f32_16x16x32_bf16(A0, t0.v, a0, 0, 0, 0);
        acc0[1] = __builtin_amdgcn_mfma_f32_16x16x32_bf16(A0, t1.v, a1, 0, 0, 0);
    }
    // LN (per row, N=32) + relu + wave-partial col-max
    {
        float g0c[2]  = { g0[m],  g0[16 + m]  };
        float be0c[2] = { be0[m], be0[16 + m] };
        float a0mx[2] = { 0.f, 0.f };
        #pragma unroll
        for (int reg = 0; reg < 4; reg++) {
            float x0 = acc0[0][reg], x1 = acc0[1][reg];
            float rs = red16sum(x0 + x1);
            float rq = red16sum(x0 * x0 + x1 * x1);
            float mu = rs * (1.f / 32.f);
            float var = rq * (1.f / 32.f) - mu * mu;
            float ri = rsqrtf(var + LN_EPS);
            #pragma unroll
            for (int ct = 0; ct < 2; ct++) {
                float v = fmaxf(fmaf(g0c[ct] * ri, acc0[ct][reg] - mu, be0c[ct]), 0.f);
                acc0[ct][reg] = v;
                a0mx[ct] = fmaxf(a0mx[ct], v);
            }
        }
        #pragma unroll
        for (int ct = 0; ct < 2; ct++) {
            float v = a0mx[ct];
            v = fmaxf(v, __shfl_xor(v, 16, 64));
            v = fmaxf(v, __shfl_xor(v, 32, 64));
            a0mx[ct] = v;
        }
        if (q == 0) { partA[w][m] = a0mx[0]; partA[w][16 + m] = a0mx[1]; }
    }
    // stage h0 (bf16) for layer-1 A fragments (wave-local rows)
    #pragma unroll
    for (int reg = 0; reg < 4; reg++) {
        int row = r0 + q * 4 + reg;
        unsigned u = packbf(acc0[0][reg], acc0[1][reg]);
        hbuf[row * 72 + m]      = (unsigned short)u;
        hbuf[row * 72 + 16 + m] = (unsigned short)(u >> 16);
    }
    __syncthreads();   // (1) partA ready

    // au1 partial: wave w covers j = w*8 .. w*8+7
    {
        float p = 0.f;
        int j0 = w * 8;
        #pragma unroll
        for (int jj = 0; jj < 8; jj++) {
            int j = j0 + jj;
            float a = fmaxf(fmaxf(partA[0][j], partA[1][j]), fmaxf(partA[2][j], partA[3][j]));
            p = fmaf(a, W1[(32 + j) * 64 + L], p);
        }
        partB[w][L] = p;
    }
    __syncthreads();   // (2) partB(au1) ready

    // ---------------- layer 1 : 64(per-row 32) -> 64 ----------------
    bf16x8 A1;
    { U4B8 c; c.u = *(const uint4*)(hbuf + (r0 + m) * 72 + q * 8); A1 = c.v; }
    f32x4 acc1[4];
    #pragma unroll
    for (int ct = 0; ct < 4; ct++) {
        U4B8 wv; wv.u = wpack[(2 + ct) * 64 + L];
        int n = ct * 16 + m;
        float au = b1[n] + ((partB[0][n] + partB[1][n]) + (partB[2][n] + partB[3][n]));
        f32x4 a = { au, au, au, au };
        acc1[ct] = __builtin_amdgcn_mfma_f32_16x16x32_bf16(A1, wv.v, a, 0, 0, 0);
    }
    {
        float g1c[4], be1c[4];
        #pragma unroll
        for (int ct = 0; ct < 4; ct++) { g1c[ct] = g1[ct * 16 + m]; be1c[ct] = be1[ct * 16 + m]; }
        float a1mx[4] = { 0.f, 0.f, 0.f, 0.f };
        #pragma unroll
        for (int reg = 0; reg < 4; reg++) {
            float rs = 0.f, rq = 0.f;
            #pragma unroll
            for (int ct = 0; ct < 4; ct++) { float x = acc1[ct][reg]; rs += x; rq = fmaf(x, x, rq); }
            rs = red16sum(rs);
            rq = red16sum(rq);
            float mu = rs * (1.f / 64.f);
            float var = rq * (1.f / 64.f) - mu * mu;
            float ri = rsqrtf(var + LN_EPS);
            #pragma unroll
            for (int ct = 0; ct < 4; ct++) {
                float v = fmaxf(fmaf(g1c[ct] * ri, acc1[ct][reg] - mu, be1c[ct]), 0.f);
                acc1[ct][reg] = v;
                a1mx[ct] = fmaxf(a1mx[ct], v);
            }
        }
        #pragma unroll
        for (int ct = 0; ct < 4; ct++) {
            float v = a1mx[ct];
            v = fmaxf(v, __shfl_xor(v, 16, 64));
            v = fmaxf(v, __shfl_xor(v, 32, 64));
            a1mx[ct] = v;
        }
        if (q == 0) {
            #pragma unroll
            for (int ct = 0; ct < 4; ct++) partA[w][ct * 16 + m] = a1mx[ct];
        }
    }
    // stage h1 (bf16), wave-local rows
    #pragma unroll
    for (int reg = 0; reg < 4; reg++) {
        int row = r0 + q * 4 + reg;
        unsigned ua = packbf(acc1[0][reg], acc1[1][reg]);
        unsigned ub = packbf(acc1[2][reg], acc1[3][reg]);
        hbuf[row * 72 + m]      = (unsigned short)ua;
        hbuf[row * 72 + 16 + m] = (unsigned short)(ua >> 16);
        hbuf[row * 72 + 32 + m] = (unsigned short)ub;
        hbuf[row * 72 + 48 + m] = (unsigned short)(ub >> 16);
    }
    __syncthreads();   // (3) partA(l1 colmax) ready

    // au2 partial: wave w covers j = w*16 .. w*16+15; outputs cols L and 64+L
    {
        float pa = 0.f, pb = 0.f;
        int j0 = w * 16;
        #pragma unroll
        for (int jj = 0; jj < 16; jj++) {
            int j = j0 + jj;
            float a = fmaxf(fmaxf(partA[0][j], partA[1][j]), fmaxf(partA[2][j], partA[3][j]));
            pa = fmaf(a, W2[(64 + j) * 128 + L],      pa);
            pb = fmaf(a, W2[(64 + j) * 128 + 64 + L], pb);
        }
        partB[w][L]      = pa;
        partB[w][64 + L] = pb;
    }
    __syncthreads();   // (4) partB(au2) ready

    // ---------------- layer 2 : 128(per-row 64) -> 128, single pass ----------------
    bf16x8 A2[2];
    #pragma unroll
    for (int ks = 0; ks < 2; ks++) {
        U4B8 c; c.u = *(const uint4*)(hbuf + (r0 + m) * 72 + ks * 32 + q * 8);
        A2[ks] = c.v;
    }
    f32x4 acc2[8];
    #pragma unroll
    for (int ct = 0; ct < 8; ct++) {
        U4B8 wa, wb;
        wa.u = wpack[(6 + ct) * 64 + L];
        wb.u = wpack[(14 + ct) * 64 + L];
        int n = ct * 16 + m;
        float au = b2[n] + ((partB[0][n] + partB[1][n]) + (partB[2][n] + partB[3][n]));
        f32x4 a = { au, au, au, au };
        a = __builtin_amdgcn_mfma_f32_16x16x32_bf16(A2[0], wa.v, a, 0, 0, 0);
        a = __builtin_amdgcn_mfma_f32_16x16x32_bf16(A2[1], wb.v, a, 0, 0, 0);
        acc2[ct] = a;
    }
    {
        float g2c[8], be2c[8];
        #pragma unroll
        for (int ct = 0; ct < 8; ct++) { g2c[ct] = g2[ct * 16 + m]; be2c[ct] = be2[ct * 16 + m]; }
        float m2[8] = { 0.f, 0.f, 0.f, 0.f, 0.f, 0.f, 0.f, 0.f };
        #pragma unroll
        for (int reg = 0; reg < 4; reg++) {
            float rs = 0.f, rq = 0.f;
            #pragma unroll
            for (int ct = 0; ct < 8; ct++) { float x = acc2[ct][reg]; rs += x; rq = fmaf(x, x, rq); }
            rs = red16sum(rs);
            rq = red16sum(rq);
            float mu = rs * (1.f / 128.f);
            float var = rq * (1.f / 128.f) - mu * mu;
            float ri = rsqrtf(var + LN_EPS);
            #pragma unroll
            for (int ct = 0; ct < 8; ct++) {
                float v = fmaxf(fmaf(g2c[ct] * ri, acc2[ct][reg] - mu, be2c[ct]), 0.f);
                m2[ct] = fmaxf(m2[ct], v);
            }
        }
        #pragma unroll
        for (int ct = 0; ct < 8; ct++) {
            float v = m2[ct];
            v = fmaxf(v, __shfl_xor(v, 16, 64));
            v = fmaxf(v, __shfl_xor(v, 32, 64));
            m2[ct] = v;
        }
        if (q == 0) {
            #pragma unroll
            for (int ct = 0; ct < 8; ct++) partA[w][ct * 16 + m] = m2[ct];
        }
    }
    __syncthreads();   // (5) partA(l2 colmax) ready

    if (tid < 128) {
        float v = fmaxf(fmaxf(partA[0][tid], partA[1][tid]),
                        fmaxf(partA[2][tid], partA[3][tid]));
        Ph[(size_t)blk * 128 + tid] = v;
    }
}

// ---------------------------------------------------------------------------
// vn_attn: ONE BLOCK PER BATCH, 1024 threads (16 waves). Every phase split
// 4-8 ways with LDS partial combines: per-thread load chains 128 -> 32,
// 4 waves/SIMD hide latency (round-6 lesson: wall == one block's serial
// chain; cross-block replication doesn't shorten it).
// ---------------------------------------------------------------------------
__global__ __launch_bounds__(1024) void vn_attn(
    const float* __restrict__ data, const float* __restrict__ Ph,
    const float* __restrict__ Wqf, const float* __restrict__ WkfT,
    const float* __restrict__ bq,
    const float* __restrict__ Wvf, const float* __restrict__ bv,
    float* __restrict__ out)
{
    extern __shared__ float shPh[];                 // [256][129] = 132096 B
    __shared__ __align__(16) float qs[256], tts[128], att[256], pb[128], sc[256];
    __shared__ __align__(16) float part[1024];
    __shared__ float red[8];
    const int b = blockIdx.x, tid = threadIdx.x;
    const float* PhB = Ph + (size_t)b * NPOLY * 128;
    const int agent = (int)data[(size_t)b * NV * LCH];

    // stage PhB -> shPh (pitch 129), coalesced float4 reads
    {
        const float4* src = (const float4*)PhB;
        #pragma unroll
        for (int it = 0; it < 8; it++) {
            int idx4 = it * 1024 + tid;             // 8192 float4 total
            float4 v = src[idx4];
            int lin = idx4 * 4;
            int p = lin >> 7, c = lin & 127;
            float* dst = shPh + p * 129 + c;
            dst[0] = v.x; dst[1] = v.y; dst[2] = v.z; dst[3] = v.w;
        }
    }
    __syncthreads();

    // q partials: thread (c = tid&255, ig = tid>>8) covers i = ig*32..+31
    {
        const int c = tid & 255, ig = tid >> 8;
        const float* pa = shPh + agent * 129 + ig * 32;
        const float* wq = Wqf + (size_t)(ig * 32) * 256 + c;
        float s0 = 0.f, s1 = 0.f, s2 = 0.f, s3 = 0.f;
        #pragma unroll
        for (int i = 0; i < 32; i += 4) {
            s0 = fmaf(pa[i],     wq[(i)     * 256], s0);
            s1 = fmaf(pa[i + 1], wq[(i + 1) * 256], s1);
            s2 = fmaf(pa[i + 2], wq[(i + 2) * 256], s2);
            s3 = fmaf(pa[i + 3], wq[(i + 3) * 256], s3);
        }
        part[ig * 256 + c] = (s0 + s1) + (s2 + s3);
    }
    __syncthreads();
    if (tid < 256)
        qs[tid] = bq[tid] + ((part[tid] + part[256 + tid]) + (part[512 + tid] + part[768 + tid]));
    __syncthreads();

    // tts partials: thread (j = tid&127, cg = tid>>7) covers c = cg*32..+31
    {
        const int j = tid & 127, cg = tid >> 7;
        const float* wk = WkfT + (size_t)(cg * 32) * 128 + j;
        const float* qp = qs + cg * 32;
        float s0 = 0.f, s1 = 0.f, s2 = 0.f, s3 = 0.f;
        #pragma unroll
        for (int c = 0; c < 32; c += 4) {
            s0 = fmaf(qp[c],     wk[(c)     * 128], s0);
            s1 = fmaf(qp[c + 1], wk[(c + 1) * 128], s1);
            s2 = fmaf(qp[c + 2], wk[(c + 2) * 128], s2);
            s3 = fmaf(qp[c + 3], wk[(c + 3) * 128], s3);
        }
        part[cg * 128 + j] = (s0 + s1) + (s2 + s3);
    }
    __syncthreads();
    if (tid < 128) {
        float s = 0.f;
        #pragma unroll
        for (int k = 0; k < 8; k++) s += part[k * 128 + tid];
        tts[tid] = s;
    }
    __syncthreads();

    // score partials: thread (p = tid&255, jg = tid>>8) covers j = jg*32..+31
    {
        const int p = tid & 255, jg = tid >> 8;
        const float* prl = shPh + p * 129 + jg * 32;
        const float* tp = tts + jg * 32;
        float s0 = 0.f, s1 = 0.f, s2 = 0.f, s3 = 0.f;
        #pragma unroll
        for (int j = 0; j < 32; j += 4) {
            s0 = fmaf(prl[j],     tp[j],     s0);
            s1 = fmaf(prl[j + 1], tp[j + 1], s1);
            s2 = fmaf(prl[j + 2], tp[j + 2], s2);
            s3 = fmaf(prl[j + 3], tp[j + 3], s3);
        }
        part[jg * 256 + p] = (s0 + s1) + (s2 + s3);
    }
    __syncthreads();
    if (tid < 256)
        sc[tid] = ((part[tid] + part[256 + tid]) + (part[512 + tid] + part[768 + tid])) * 0.0625f;
    __syncthreads();

    // softmax over 256 scores (waves 0-3 own writes; others compute redundantly)
    float svv = sc[tid & 255];
    float mx = svv;
    #pragma unroll
    for (int s = 1; s < 64; s <<= 1) mx = fmaxf(mx, __shfl_xor(mx, s, 64));
    if (tid < 256 && (tid & 63) == 0) red[tid >> 6] = mx;
    __syncthreads();
    mx = fmaxf(fmaxf(red[0], red[1]), fmaxf(red[2], red[3]));
    float e = expf(svv - mx);
    float sm = e;
    #pragma unroll
    for (int s = 1; s < 64; s <<= 1) sm += __shfl_xor(sm, s, 64);
    if (tid < 256 && (tid & 63) == 0) red[4 + (tid >> 6)] = sm;
    __syncthreads();
    {
        const float tot = red[4] + red[5] + red[6] + red[7];
        if (tid < 256) att[tid] = e / tot;
    }
    __syncthreads();

    // pb partials: thread (c = tid&127, pg = tid>>7) covers p = pg*32..+31
    {
        const int c = tid & 127, pg = tid >> 7;
        const float* ap = att + pg * 32;
        const float* pp = shPh + (size_t)(pg * 32) * 129 + c;
        float s0 = 0.f, s1 = 0.f, s2 = 0.f, s3 = 0.f;
        #pragma unroll
        for (int p = 0; p < 32; p += 4) {
            s0 = fmaf(ap[p],     pp[(p)     * 129], s0);
            s1 = fmaf(ap[p + 1], pp[(p + 1) * 129], s1);
            s2 = fmaf(ap[p + 2], pp[(p + 2) * 129], s2);
            s3 = fmaf(ap[p + 3], pp[(p + 3) * 129], s3);
        }
        part[pg * 128 + c] = (s0 + s1) + (s2 + s3);
    }
    __syncthreads();
    if (tid < 128) {
        float s = 0.f;
        #pragma unroll
        for (int k = 0; k < 8; k++) s += part[k * 128 + tid];
        pb[tid] = s;
    }
    __syncthreads();

    // out partials: thread (c = tid&255, jg = tid>>8) covers j = jg*32..+31
    {
        const int c = tid & 255, jg = tid >> 8;
        const float* wv = Wvf + (size_t)(jg * 32) * 256 + c;
        const float* pbp = pb + jg * 32;
        float s0 = 0.f, s1 = 0.f, s2 = 0.f, s3 = 0.f;
        #pragma unroll
        for (int j = 0; j < 32; j += 4) {
            s0 = fmaf(pbp[j],     wv[(j)     * 256], s0);
            s1 = fmaf(pbp[j + 1], wv[(j + 1) * 256], s1);
            s2 = fmaf(pbp[j + 2], wv[(j + 2) * 256], s2);
            s3 = fmaf(pbp[j + 3], wv[(j + 3) * 256], s3);
        }
        part[jg * 256 + c] = (s0 + s1) + (s2 + s3);
    }
    __syncthreads();
    if (tid < 256)
        out[(size_t)b * 256 + tid] =
            bv[tid] + ((part[tid] + part[256 + tid]) + (part[512 + tid] + part[768 + tid]));
}

extern "C" void kernel_launch(void* const* d_in, const int* in_sizes, int n_in,
                              void* d_out, int out_size, void* d_ws, size_t ws_size,
                              hipStream_t stream)
{
    const float* data = (const float*)d_in[0];
    const float* W0 = (const float*)d_in[1];
    const float* b0 = (const float*)d_in[2];
    const float* g0 = (const float*)d_in[3];
    const float* be0= (const float*)d_in[4];
    const float* W1 = (const float*)d_in[5];
    const float* b1 = (const float*)d_in[6];
    const float* g1 = (const float*)d_in[7];
    const float* be1= (const float*)d_in[8];
    const float* W2 = (const float*)d_in[9];
    const float* b2 = (const float*)d_in[10];
    const float* g2 = (const float*)d_in[11];
    const float* be2= (const float*)d_in[12];
    const float* Wq = (const float*)d_in[13];
    const float* bq = (const float*)d_in[14];
    const float* Wk = (const float*)d_in[15];
    const float* bk = (const float*)d_in[16];
    const float* Wv = (const float*)d_in[17];
    const float* bv = (const float*)d_in[18];
    (void)bk;

    char* wsb = (char*)d_ws;
    float* Ph    = (float*)(wsb);                  // 4 MB
    float* Wqf   = (float*)(wsb + 4194304);        // 128 KB
    float* WkfT  = (float*)(wsb + 4325376);        // 128 KB
    float* Wvf   = (float*)(wsb + 4456448);        // 128 KB
    uint4* wpack = (uint4*)(wsb + 4653568);        // 22 KB

    static int attn_attr_set = 0;
    if (!attn_attr_set) {
        hipFuncSetAttribute((const void*)vn_attn,
                            hipFuncAttributeMaxDynamicSharedMemorySize, 132096);
        attn_attr_set = 1;
    }

    vn_prep<<<390, 256, 0, stream>>>(W0, W1, W2, Wq, Wk, Wv, Wvf, Wqf, WkfT, wpack);
    vn_mlp<<<32 * NPOLY, 256, 0, stream>>>(data, wpack,
                                           b0, g0, be0,
                                           W1, b1, g1, be1,
                                           W2, b2, g2, be2, Ph);
    vn_attn<<<32, 1024, 132096, stream>>>(data, Ph, Wqf, WkfT, bq, Wvf, bv, (float*)d_out);
}